// Round 6
// baseline (229.708 us; speedup 1.0000x reference)
//
#include <hip/hip_runtime.h>
#include <cstdint>

#define N_ROWS 8192
#define DIMS   512
#define NT     256

typedef unsigned short u16;
typedef __attribute__((ext_vector_type(8))) short s8v;            // 8 bf16 MFMA A/B frag
typedef __attribute__((ext_vector_type(4))) float f4v;            // MFMA C/D frag
typedef __attribute__((ext_vector_type(8))) unsigned short u16x8;

__device__ __forceinline__ u16 f2bf(float f) {
    unsigned u = __float_as_uint(f);
    unsigned r = (u + 0x7fff + ((u >> 16) & 1)) >> 16;
    return (u16)r;
}
__device__ __forceinline__ float bf2f(u16 h) { return __uint_as_float(((unsigned)h) << 16); }

__device__ __forceinline__ void gl16(const void* g, void* l) {
    auto gp = (const __attribute__((address_space(1))) unsigned int*)(uintptr_t)g;
    auto lp = (__attribute__((address_space(3))) unsigned int*)(uintptr_t)l;
    __builtin_amdgcn_global_load_lds(gp, lp, 16, 0, 0);
}

// ============ convert + transpose (hi only) + diag partials (plain stores) ============
__global__ __launch_bounds__(NT) void convert_diag(
    const float* __restrict__ X, const float* __restrict__ Y,
    u16* __restrict__ Xh, u16* __restrict__ Yh,
    float* __restrict__ diagPart)
{
    const int b  = blockIdx.x;
    const int nt = b & 127;
    const int dt = b >> 7;

    __shared__ float tx[64][65];
    __shared__ float ty[64][65];

    const int tid = threadIdx.x;
    const int c4 = tid & 15, rr = tid >> 4;
#pragma unroll
    for (int rp = 0; rp < 4; ++rp) {
        const int row = rp * 16 + rr;
        const size_t gbase = (size_t)(nt * 64 + row) * DIMS + dt * 64 + c4 * 4;
        float4 vx = *(const float4*)&X[gbase];
        float4 vy = *(const float4*)&Y[gbase];
        tx[row][c4 * 4 + 0] = vx.x; tx[row][c4 * 4 + 1] = vx.y;
        tx[row][c4 * 4 + 2] = vx.z; tx[row][c4 * 4 + 3] = vx.w;
        ty[row][c4 * 4 + 0] = vy.x; ty[row][c4 * 4 + 1] = vy.y;
        ty[row][c4 * 4 + 2] = vy.z; ty[row][c4 * 4 + 3] = vy.w;
        float d = vx.x * vy.x + vx.y * vy.y + vx.z * vy.z + vx.w * vy.w;
        d += __shfl_xor(d, 1); d += __shfl_xor(d, 2);
        d += __shfl_xor(d, 4); d += __shfl_xor(d, 8);
        if (c4 == 0) diagPart[dt * N_ROWS + nt * 64 + row] = d;
    }
    __syncthreads();

    const int d = tid >> 2, ns = (tid & 3) * 16;
    const size_t ob = (size_t)(dt * 64 + d) * N_ROWS + nt * 64 + ns;
#pragma unroll
    for (int mat = 0; mat < 2; ++mat) {
        float (*tp)[65] = mat ? ty : tx;
        u16* Oh = mat ? Yh : Xh;
        u16x8 h0, h1;
#pragma unroll
        for (int i = 0; i < 8; ++i) {
            h0[i] = f2bf(tp[ns + i][d]);
            h1[i] = f2bf(tp[ns + 8 + i][d]);
        }
        *(u16x8*)&Oh[ob]     = h0;
        *(u16x8*)&Oh[ob + 8] = h1;
    }
}

// ============ symmetric bf16 syrk + fused last-block reduction ============
// grid (nsplit, 10, 2). BK=32 double-buffer, 32 KB LDS, 4 blocks/CU resident.
// Epilogue mode 0: bf16 store to private slab slot, then the 64th block per
// tile-pair p reduces pair p; the 10th pair-reducer folds diag + writes loss.
// mode 1: fp32 atomicAdd into Aslab/Bslab (fallback tier).
__global__ __launch_bounds__(NT, 4) void syrk_bf16(
    const u16* __restrict__ Xh, const u16* __restrict__ Yh,
    u16* __restrict__ slabs, float* __restrict__ Aslab, float* __restrict__ Bslab,
    int* __restrict__ cnt, float* __restrict__ pairS,
    const float* __restrict__ diagPart, float* __restrict__ out,
    int nsplit, int mode)
{
    __shared__ u16 smem[2 * 2 * 4096];   // [stage][stripe][128*32] = 32 KB

    const int tid = threadIdx.x;
    const int s = blockIdx.x, p = blockIdx.y, mat = blockIdx.z;
    const int ti_t[10] = {0,0,0,0,1,1,1,2,2,3};
    const int tj_t[10] = {0,1,2,3,1,2,3,2,3,3};
    const int m0 = ti_t[p] * 128, n0 = tj_t[p] * 128;
    const u16* Th = mat ? Yh : Xh;

    const int w = tid >> 6, L = tid & 63;
    const int wm = (w >> 1) * 64, wn = (w & 1) * 64;
    const int lrow = L & 15, q = L >> 4;

    f4v acc[4][4];
#pragma unroll
    for (int i = 0; i < 4; ++i)
#pragma unroll
        for (int j = 0; j < 4; ++j)
            acc[i][j] = (f4v){0.f, 0.f, 0.f, 0.f};

    const int kchunk = N_ROWS / nsplit;
    const int kk0 = s * kchunk;
    const int nIter = kchunk / 32;

    auto loadStage = [&](int buf, int kb) {
        u16* dA = smem + buf * 8192;
        u16* dB = dA + 4096;
#pragma unroll
        for (int j = 0; j < 2; ++j) {
            const int slot = j * 256 + tid;
            const int row  = slot >> 2;
            const int c    = (slot & 3) ^ ((row >> 1) & 3);
            gl16(Th + (size_t)(m0 + row) * N_ROWS + kb + c * 8, dA + slot * 8);
            gl16(Th + (size_t)(n0 + row) * N_ROWS + kb + c * 8, dB + slot * 8);
        }
    };

    loadStage(0, kk0);

    for (int it = 0; it < nIter; ++it) {
        __syncthreads();                 // drains stage-it gl16s, syncs block
        if (it + 1 < nIter) loadStage((it + 1) & 1, kk0 + (it + 1) * 32);

        const u16* SA = smem + (it & 1) * 8192;
        const u16* SB = SA + 4096;
        s8v a[4], b[4];
#pragma unroll
        for (int t = 0; t < 4; ++t) {
            const int rowA = wm + t * 16 + lrow;
            const int rowB = wn + t * 16 + lrow;
            const int pA = q ^ ((rowA >> 1) & 3);
            const int pB = q ^ ((rowB >> 1) & 3);
            a[t] = *(const s8v*)&SA[rowA * 32 + pA * 8];
            b[t] = *(const s8v*)&SB[rowB * 32 + pB * 8];
        }
#pragma unroll
        for (int ti2 = 0; ti2 < 4; ++ti2)
#pragma unroll
            for (int tj2 = 0; tj2 < 4; ++tj2)
                acc[ti2][tj2] = __builtin_amdgcn_mfma_f32_16x16x32_bf16(
                    a[ti2], b[tj2], acc[ti2][tj2], 0, 0, 0);
    }

    if (mode == 1) {
        float* G = mat ? Bslab : Aslab;
#pragma unroll
        for (int ti2 = 0; ti2 < 4; ++ti2)
#pragma unroll
            for (int tj2 = 0; tj2 < 4; ++tj2)
#pragma unroll
                for (int r = 0; r < 4; ++r) {
                    const int row = m0 + wm + ti2 * 16 + q * 4 + r;
                    const int col = n0 + wn + tj2 * 16 + lrow;
                    atomicAdd(&G[row * DIMS + col], acc[ti2][tj2][r]);
                }
        return;
    }

    // ---- mode 0: plain bf16 store to private slab slot ----
    u16* dst = slabs + ((size_t)(s * 2 + mat) * 10 + p) * 16384;
#pragma unroll
    for (int ti2 = 0; ti2 < 4; ++ti2)
#pragma unroll
        for (int tj2 = 0; tj2 < 4; ++tj2)
#pragma unroll
            for (int r = 0; r < 4; ++r) {
                const int rl = wm + ti2 * 16 + q * 4 + r;
                const int cl = wn + tj2 * 16 + lrow;
                dst[rl * 128 + cl] = f2bf(acc[ti2][tj2][r]);
            }

    // ---- last block per pair p (of nsplit*2) reduces pair p ----
    __shared__ int sflag;
    __shared__ float red[3][4];
    __syncthreads();                          // all stores issued & complete
    if (tid == 0) {
        __threadfence();                      // release: L2 writeback
        sflag = (atomicAdd(&cnt[p], 1) == nsplit * 2 - 1);
    }
    __syncthreads();
    if (!sflag) return;
    __threadfence();                          // acquire

    const float wp = ((p == 0) | (p == 4) | (p == 7) | (p == 9)) ? 1.f : 2.f;
    float sS = 0.f;
#pragma unroll
    for (int g8 = 0; g8 < 8; ++g8) {
        const int e8 = (g8 * 256 + tid) * 8;
        float a8[8] = {}, b8[8] = {};
        for (int sb = 0; sb < nsplit; sb += 8) {
            u16x8 va[8], vb[8];
#pragma unroll
            for (int i = 0; i < 8; ++i) {
                va[i] = *(const u16x8*)&slabs[((size_t)((sb + i) * 2 + 0) * 10 + p) * 16384 + e8];
                vb[i] = *(const u16x8*)&slabs[((size_t)((sb + i) * 2 + 1) * 10 + p) * 16384 + e8];
            }
#pragma unroll
            for (int i = 0; i < 8; ++i)
#pragma unroll
                for (int j = 0; j < 8; ++j) {
                    a8[j] += bf2f(va[i][j]);
                    b8[j] += bf2f(vb[i][j]);
                }
        }
#pragma unroll
        for (int j = 0; j < 8; ++j) sS += a8[j] * b8[j];
    }
    sS *= wp;

    for (int off = 32; off; off >>= 1) sS += __shfl_xor(sS, off);
    if (L == 0) red[0][w] = sS;
    __syncthreads();
    if (tid == 0) {
        pairS[p] = red[0][0] + red[0][1] + red[0][2] + red[0][3];
        __threadfence();
        sflag = (atomicAdd(&cnt[15], 1) == 9);
    }
    __syncthreads();
    if (!sflag) return;
    __threadfence();

    // ---- final block: diag reduction + loss ----
    float sD = 0.f, sD2 = 0.f;
    for (int r = tid; r < N_ROWS; r += 256) {
        float d = 0.f;
#pragma unroll
        for (int dt = 0; dt < 8; ++dt) d += diagPart[dt * N_ROWS + r];
        sD += d; sD2 += d * d;
    }
    for (int off = 32; off; off >>= 1) {
        sD  += __shfl_xor(sD,  off);
        sD2 += __shfl_xor(sD2, off);
    }
    if (L == 0) { red[1][w] = sD; red[2][w] = sD2; }
    __syncthreads();
    if (tid == 0) {
        const double ds  = (double)(red[1][0] + red[1][1] + red[1][2] + red[1][3]);
        const double dsq = (double)(red[2][0] + red[2][1] + red[2][2] + red[2][3]);
        double S = 0.0;
        for (int i = 0; i < 10; ++i) S += (double)pairS[i];
        const double loss =
            (S - dsq) / ((double)N_ROWS * (double)(N_ROWS - 1)) - 2.0 * ds / (double)N_ROWS;
        out[0] = (float)loss;
    }
}

// ============ pass2 for atomic-slab tier (fp32 slabs + diagPart) ============
__global__ __launch_bounds__(256) void pass2_sym(
    const float* __restrict__ Aslab, const float* __restrict__ Bslab,
    const float* __restrict__ diagPart, float4* __restrict__ partials)
{
    const int tid = threadIdx.x;
    const int g   = blockIdx.x * 256 + tid;        // 0..20479
    float sS = 0.f, sD = 0.f, sD2 = 0.f;
    for (int e = g; e < DIMS * DIMS; e += 20480) {
        const int r = e >> 9, c = e & 511;
        const float w = ((r >> 7) == (c >> 7)) ? 1.f : 2.f;
        sS += w * Aslab[e] * Bslab[e];
    }
    if (g < N_ROWS) {
        float d = 0.f;
#pragma unroll
        for (int dt = 0; dt < 8; ++dt) d += diagPart[dt * N_ROWS + g];
        sD = d; sD2 = d * d;
    }
    for (int off = 32; off; off >>= 1) {
        sS  += __shfl_xor(sS,  off);
        sD  += __shfl_xor(sD,  off);
        sD2 += __shfl_xor(sD2, off);
    }
    __shared__ float red[3][4];
    if ((tid & 63) == 0) {
        red[0][tid >> 6] = sS; red[1][tid >> 6] = sD; red[2][tid >> 6] = sD2;
    }
    __syncthreads();
    if (tid == 0)
        partials[blockIdx.x] = make_float4(
            red[0][0] + red[0][1] + red[0][2] + red[0][3],
            red[1][0] + red[1][1] + red[1][2] + red[1][3],
            red[2][0] + red[2][1] + red[2][2] + red[2][3], 0.f);
}

__global__ void finalize_partials(const float4* __restrict__ partials, int nb,
                                  float* __restrict__ out)
{
    const int tid = threadIdx.x;   // 64 threads
    float sS = 0.f, sD = 0.f, sD2 = 0.f;
    for (int i = tid; i < nb; i += 64) {
        float4 v = partials[i];
        sS += v.x; sD += v.y; sD2 += v.z;
    }
    for (int off = 32; off; off >>= 1) {
        sS  += __shfl_xor(sS,  off);
        sD  += __shfl_xor(sD,  off);
        sD2 += __shfl_xor(sD2, off);
    }
    if (tid == 0) {
        const double offd = (double)sS - (double)sD2;
        const double loss =
            offd / ((double)N_ROWS * (double)(N_ROWS - 1)) - 2.0 * (double)sD / (double)N_ROWS;
        out[0] = (float)loss;
    }
}

// ============ fp32 vector fallback (round-1, proven) ============
#define TILE   64
#define KSPLIT 8
#define KCHUNK (N_ROWS / KSPLIT)
#define KB     16
__global__ __launch_bounds__(NT) void syrk_kernel(
    const float* __restrict__ X, const float* __restrict__ Y,
    float* __restrict__ Abase, float* __restrict__ Bbase, int useSlabs)
{
    const int tid = threadIdx.x;
    const int ta  = blockIdx.x >> 3;
    const int tb  = blockIdx.x & 7;
    const int s   = blockIdx.y;
    const int ca  = tid & 15;
    const int cb  = tid >> 4;

    __shared__ float4 sXA[KB * 16];
    __shared__ float4 sXB[KB * 16];
    __shared__ float4 sYA[KB * 16];
    __shared__ float4 sYB[KB * 16];

    const float4* Xv = (const float4*)X;
    const float4* Yv = (const float4*)Y;

    float aA[4][4] = {};
    float aB[4][4] = {};

    const int r0     = s * KCHUNK;
    const int rowOfT = tid >> 4;
    const int colOfT = tid & 15;

    for (int it = 0; it < KCHUNK / KB; ++it) {
        const int row  = r0 + it * KB + rowOfT;
        const int base = row * (DIMS / 4);
        __syncthreads();
        sXA[tid] = Xv[base + ta * 16 + colOfT];
        sXB[tid] = Xv[base + tb * 16 + colOfT];
        sYA[tid] = Yv[base + ta * 16 + colOfT];
        sYB[tid] = Yv[base + tb * 16 + colOfT];
        __syncthreads();
#pragma unroll
        for (int k = 0; k < KB; ++k) {
            float4 xa4 = sXA[k * 16 + ca];
            float4 xb4 = sXB[k * 16 + cb];
            float4 ya4 = sYA[k * 16 + ca];
            float4 yb4 = sYB[k * 16 + cb];
            float xa[4] = {xa4.x, xa4.y, xa4.z, xa4.w};
            float xb[4] = {xb4.x, xb4.y, xb4.z, xb4.w};
            float ya[4] = {ya4.x, ya4.y, ya4.z, ya4.w};
            float yb[4] = {yb4.x, yb4.y, yb4.z, yb4.w};
#pragma unroll
            for (int i = 0; i < 4; ++i)
#pragma unroll
                for (int j = 0; j < 4; ++j) {
                    aA[i][j] = fmaf(xa[i], xb[j], aA[i][j]);
                    aB[i][j] = fmaf(ya[i], yb[j], aB[i][j]);
                }
        }
    }

    const size_t slabElems = (size_t)DIMS * DIMS;
    float* Adst = Abase + (useSlabs ? (size_t)s * slabElems : 0);
    float* Bdst = Bbase + (useSlabs ? (size_t)s * slabElems : 0);

#pragma unroll
    for (int i = 0; i < 4; ++i) {
        const int    ag    = ta * TILE + ca * 4 + i;
        const int    cbase = tb * TILE + cb * 4;
        const size_t idx   = (size_t)ag * DIMS + cbase;
        if (useSlabs) {
            *(float4*)(Adst + idx) = make_float4(aA[i][0], aA[i][1], aA[i][2], aA[i][3]);
            *(float4*)(Bdst + idx) = make_float4(aB[i][0], aB[i][1], aB[i][2], aB[i][3]);
        } else {
#pragma unroll
            for (int j = 0; j < 4; ++j) {
                atomicAdd(Adst + idx + j, aA[i][j]);
                atomicAdd(Bdst + idx + j, aB[i][j]);
            }
        }
    }
}

__global__ __launch_bounds__(256) void diag_kernel(
    const float* __restrict__ X, const float* __restrict__ Y,
    float* __restrict__ scal)
{
    const int tid  = threadIdx.x;
    const int lane = tid & 63;
    const int wave = blockIdx.x * 4 + (tid >> 6);
    const float4* Xv = (const float4*)X;
    const float4* Yv = (const float4*)Y;

    float dsum = 0.f, dsq = 0.f;
    for (int r = 0; r < 8; ++r) {
        const int row  = wave * 8 + r;
        const int base = row * (DIMS / 4) + lane * 2;
        float4 x0 = Xv[base], x1 = Xv[base + 1];
        float4 y0 = Yv[base], y1 = Yv[base + 1];
        float v = x0.x * y0.x + x0.y * y0.y + x0.z * y0.z + x0.w * y0.w
                + x1.x * y1.x + x1.y * y1.y + x1.z * y1.z + x1.w * y1.w;
        for (int off = 32; off; off >>= 1) v += __shfl_xor(v, off);
        if (lane == 0) { dsum += v; dsq += v * v; }
    }
    if (lane == 0) {
        atomicAdd(scal + 0, dsum);
        atomicAdd(scal + 1, dsq);
    }
}

__global__ __launch_bounds__(256) void pass2_kernel(
    const float* __restrict__ Abase, const float* __restrict__ Bbase,
    float* __restrict__ scal, int nslab)
{
    const int tid = threadIdx.x;
    const int g   = blockIdx.x * 256 + tid;
    const size_t slabElems = (size_t)DIMS * DIMS;
    float local = 0.f;
    for (int e = g; e < (int)slabElems; e += 65536) {
        float a = 0.f, b = 0.f;
        for (int s2 = 0; s2 < nslab; ++s2) {
            a += Abase[(size_t)s2 * slabElems + e];
            b += Bbase[(size_t)s2 * slabElems + e];
        }
        local += a * b;
    }
    for (int off = 32; off; off >>= 1) local += __shfl_xor(local, off);
    __shared__ float red[4];
    if ((tid & 63) == 0) red[tid >> 6] = local;
    __syncthreads();
    if (tid == 0) atomicAdd(scal + 2, red[0] + red[1] + red[2] + red[3]);
}

__global__ void finalize_kernel(const float* __restrict__ scal,
                                float* __restrict__ out)
{
    if (threadIdx.x == 0 && blockIdx.x == 0) {
        const double S   = (double)scal[2];
        const double dsq = (double)scal[1];
        const double ds  = (double)scal[0];
        const double off = S - dsq;
        const double loss =
            off / ((double)N_ROWS * (double)(N_ROWS - 1)) - 2.0 * ds / (double)N_ROWS;
        out[0] = (float)loss;
    }
}

extern "C" void kernel_launch(void* const* d_in, const int* in_sizes, int n_in,
                              void* d_out, int out_size, void* d_ws, size_t ws_size,
                              hipStream_t stream)
{
    const float* X = (const float*)d_in[0];
    const float* Y = (const float*)d_in[1];
    float* out = (float*)d_out;
    float* wsf = (float*)d_ws;

    const size_t trElems = (size_t)DIMS * N_ROWS;             // 4,194,304 bf16/matrix
    // Layout: [cnt 16 int | pairS 16 f | pad to 64 f | diagPart 8x8192 f | Xh | Yh | slabs]
    const size_t hdrF   = 64;
    const size_t diagF  = 8 * N_ROWS;
    const size_t coreB  = (hdrF + diagF) * sizeof(float) + 2 * trElems * sizeof(u16);
    auto slabB = [](int ns) { return (size_t)ns * 2 * 10 * 16384 * sizeof(u16); };

    int*    cnt      = (int*)wsf;        // cnt[0..9] per-pair, cnt[15] second level
    float*  pairS    = wsf + 16;
    float*  diagPart = wsf + hdrF;
    u16* Xh = (u16*)(diagPart + diagF);
    u16* Yh = Xh + trElems;

    int nsplit = 0;
    if      (ws_size >= coreB + slabB(32)) nsplit = 32;
    else if (ws_size >= coreB + slabB(16)) nsplit = 16;

    if (nsplit) {
        // primary: 3 dispatches total (counter memset, convert, fused syrk)
        u16* slabs = (u16*)(Yh + trElems);
        hipMemsetAsync(cnt, 0, 64, stream);
        convert_diag<<<1024, NT, 0, stream>>>(X, Y, Xh, Yh, diagPart);
        syrk_bf16<<<dim3(nsplit, 10, 2), NT, 0, stream>>>(
            Xh, Yh, slabs, nullptr, nullptr, cnt, pairS, diagPart, out, nsplit, 0);
    } else if (ws_size >= coreB + 2 * (size_t)DIMS * DIMS * sizeof(float)) {
        // atomic tier: fp32 A/B slabs
        float* Aslab = (float*)(Yh + trElems);
        float* Bslab = Aslab + DIMS * DIMS;
        float4* partials = (float4*)(wsf + 16);  // 80 float4 = 320 f (fits before diagPart? no) 
        // place partials safely after diagPart region is NOT needed here since slabs
        // tier layout differs; reuse pairS..diag area: put partials at wsf (overwrites cnt, unused)
        partials = (float4*)wsf;                 // 80 float4 = 1280 B < hdrF+diagF region start OK? 320f > 64f -> overlaps diagPart!
        // -> use dedicated区域 after Bslab instead:
        partials = (float4*)(Bslab + DIMS * DIMS);
        hipMemsetAsync(Aslab, 0, 2 * (size_t)DIMS * DIMS * sizeof(float), stream);
        convert_diag<<<1024, NT, 0, stream>>>(X, Y, Xh, Yh, diagPart);
        syrk_bf16<<<dim3(32, 10, 2), NT, 0, stream>>>(
            Xh, Yh, nullptr, Aslab, Bslab, cnt, pairS, diagPart, out, 32, 1);
        pass2_sym<<<80, 256, 0, stream>>>(Aslab, Bslab, diagPart, partials);
        finalize_partials<<<1, 64, 0, stream>>>(partials, 80, out);
    } else {
        // fp32 vector fallback (round-1 path)
        const size_t slabElems = (size_t)DIMS * DIMS;
        const size_t hdr = 64;
        const bool slabs2 = ws_size >= (hdr + 16 * slabElems) * sizeof(float);
        const int  nslab = slabs2 ? KSPLIT : 1;
        float* Abase = wsf + hdr;
        float* Bbase = Abase + (size_t)nslab * slabElems;

        hipMemsetAsync(d_ws, 0, hdr * sizeof(float), stream);
        if (!slabs2) hipMemsetAsync(Abase, 0, 2 * slabElems * sizeof(float), stream);

        dim3 sg(64, KSPLIT);
        syrk_kernel<<<sg, NT, 0, stream>>>(X, Y, Abase, Bbase, slabs2 ? 1 : 0);
        diag_kernel<<<256, 256, 0, stream>>>(X, Y, wsf);
        pass2_kernel<<<256, 256, 0, stream>>>(Abase, Bbase, wsf, nslab);
        finalize_kernel<<<1, 64, 0, stream>>>(wsf, out);
    }
}

// Round 7
// 99.695 us; speedup vs baseline: 2.3041x; 2.3041x over previous
//
#include <hip/hip_runtime.h>
#include <cstdint>

#define N_ROWS 8192
#define DIMS   512
#define NT     256

typedef unsigned short u16;
typedef __attribute__((ext_vector_type(8))) short s8v;            // 8 bf16 MFMA A/B frag
typedef __attribute__((ext_vector_type(4))) float f4v;            // MFMA C/D frag
typedef __attribute__((ext_vector_type(8))) unsigned short u16x8;

__device__ __forceinline__ u16 f2bf(float f) {
    unsigned u = __float_as_uint(f);
    unsigned r = (u + 0x7fff + ((u >> 16) & 1)) >> 16;
    return (u16)r;
}
__device__ __forceinline__ float bf2f(u16 h) { return __uint_as_float(((unsigned)h) << 16); }

__device__ __forceinline__ void gl16(const void* g, void* l) {
    auto gp = (const __attribute__((address_space(1))) unsigned int*)(uintptr_t)g;
    auto lp = (__attribute__((address_space(3))) unsigned int*)(uintptr_t)l;
    __builtin_amdgcn_global_load_lds(gp, lp, 16, 0, 0);
}

// ============ convert + transpose (hi only) + diag partials + cnt zeroing ============
// grid: 1024 blocks (nt 0..127, dt 0..7). Writes Xh/Yh [512][8192] bf16 and
// diagPart[dt][8192] (each element written exactly once). Block 0 zeroes cnt
// (visible to pass2 by stream ordering -> no memset dispatch needed).
__global__ __launch_bounds__(NT) void convert_diag(
    const float* __restrict__ X, const float* __restrict__ Y,
    u16* __restrict__ Xh, u16* __restrict__ Yh,
    float* __restrict__ diagPart, int* __restrict__ cnt)
{
    const int b  = blockIdx.x;
    const int nt = b & 127;
    const int dt = b >> 7;
    const int tid = threadIdx.x;

    if (b == 0 && tid < 16) cnt[tid] = 0;

    __shared__ float tx[64][65];
    __shared__ float ty[64][65];

    const int c4 = tid & 15, rr = tid >> 4;
#pragma unroll
    for (int rp = 0; rp < 4; ++rp) {
        const int row = rp * 16 + rr;
        const size_t gbase = (size_t)(nt * 64 + row) * DIMS + dt * 64 + c4 * 4;
        float4 vx = *(const float4*)&X[gbase];
        float4 vy = *(const float4*)&Y[gbase];
        tx[row][c4 * 4 + 0] = vx.x; tx[row][c4 * 4 + 1] = vx.y;
        tx[row][c4 * 4 + 2] = vx.z; tx[row][c4 * 4 + 3] = vx.w;
        ty[row][c4 * 4 + 0] = vy.x; ty[row][c4 * 4 + 1] = vy.y;
        ty[row][c4 * 4 + 2] = vy.z; ty[row][c4 * 4 + 3] = vy.w;
        float d = vx.x * vy.x + vx.y * vy.y + vx.z * vy.z + vx.w * vy.w;
        d += __shfl_xor(d, 1); d += __shfl_xor(d, 2);
        d += __shfl_xor(d, 4); d += __shfl_xor(d, 8);
        if (c4 == 0) diagPart[dt * N_ROWS + nt * 64 + row] = d;
    }
    __syncthreads();

    const int d = tid >> 2, ns = (tid & 3) * 16;
    const size_t ob = (size_t)(dt * 64 + d) * N_ROWS + nt * 64 + ns;
#pragma unroll
    for (int mat = 0; mat < 2; ++mat) {
        float (*tp)[65] = mat ? ty : tx;
        u16* Oh = mat ? Yh : Xh;
        u16x8 h0, h1;
#pragma unroll
        for (int i = 0; i < 8; ++i) {
            h0[i] = f2bf(tp[ns + i][d]);
            h1[i] = f2bf(tp[ns + 8 + i][d]);
        }
        *(u16x8*)&Oh[ob]     = h0;
        *(u16x8*)&Oh[ob + 8] = h1;
    }
}

// ============ symmetric bf16 syrk, BK=32 double-buffer, 32 KB LDS (R5-proven) ============
// grid (nsplit, 10, 2): x = k-split, y = upper tile pair, z = matrix.
// 4 blocks/CU resident. Per wave 64x64 = 4x4 16x16x32 tiles, 16 MFMA/iter.
// LDS chunk XOR swizzle c_phys = c ^ ((row>>1)&3) -> conflict-free frag reads.
// mode 0: bf16 store to private slab slot; mode 1: fp32 atomicAdd (fallback).
__global__ __launch_bounds__(NT, 4) void syrk_bf16(
    const u16* __restrict__ Xh, const u16* __restrict__ Yh,
    u16* __restrict__ slabs, float* __restrict__ Aslab, float* __restrict__ Bslab,
    int kchunk, int mode)
{
    __shared__ u16 smem[2 * 2 * 4096];   // [stage][stripe][128*32] = 32 KB

    const int tid = threadIdx.x;
    const int s = blockIdx.x, p = blockIdx.y, mat = blockIdx.z;
    const int ti_t[10] = {0,0,0,0,1,1,1,2,2,3};
    const int tj_t[10] = {0,1,2,3,1,2,3,2,3,3};
    const int m0 = ti_t[p] * 128, n0 = tj_t[p] * 128;
    const u16* Th = mat ? Yh : Xh;

    const int w = tid >> 6, L = tid & 63;
    const int wm = (w >> 1) * 64, wn = (w & 1) * 64;
    const int lrow = L & 15, q = L >> 4;

    f4v acc[4][4];
#pragma unroll
    for (int i = 0; i < 4; ++i)
#pragma unroll
        for (int j = 0; j < 4; ++j)
            acc[i][j] = (f4v){0.f, 0.f, 0.f, 0.f};

    const int kk0 = s * kchunk;
    const int nIter = kchunk / 32;

    auto loadStage = [&](int buf, int kb) {
        u16* dA = smem + buf * 8192;
        u16* dB = dA + 4096;
#pragma unroll
        for (int j = 0; j < 2; ++j) {
            const int slot = j * 256 + tid;
            const int row  = slot >> 2;
            const int c    = (slot & 3) ^ ((row >> 1) & 3);
            gl16(Th + (size_t)(m0 + row) * N_ROWS + kb + c * 8, dA + slot * 8);
            gl16(Th + (size_t)(n0 + row) * N_ROWS + kb + c * 8, dB + slot * 8);
        }
    };

    loadStage(0, kk0);

    for (int it = 0; it < nIter; ++it) {
        __syncthreads();                 // drains stage-it gl16s, syncs block
        if (it + 1 < nIter) loadStage((it + 1) & 1, kk0 + (it + 1) * 32);

        const u16* SA = smem + (it & 1) * 8192;
        const u16* SB = SA + 4096;
        s8v a[4], b[4];
#pragma unroll
        for (int t = 0; t < 4; ++t) {
            const int rowA = wm + t * 16 + lrow;
            const int rowB = wn + t * 16 + lrow;
            const int pA = q ^ ((rowA >> 1) & 3);
            const int pB = q ^ ((rowB >> 1) & 3);
            a[t] = *(const s8v*)&SA[rowA * 32 + pA * 8];
            b[t] = *(const s8v*)&SB[rowB * 32 + pB * 8];
        }
#pragma unroll
        for (int ti2 = 0; ti2 < 4; ++ti2)
#pragma unroll
            for (int tj2 = 0; tj2 < 4; ++tj2)
                acc[ti2][tj2] = __builtin_amdgcn_mfma_f32_16x16x32_bf16(
                    a[ti2], b[tj2], acc[ti2][tj2], 0, 0, 0);
    }

    if (mode == 0) {
        u16* dst = slabs + ((size_t)(s * 2 + mat) * 10 + p) * 16384;
#pragma unroll
        for (int ti2 = 0; ti2 < 4; ++ti2)
#pragma unroll
            for (int tj2 = 0; tj2 < 4; ++tj2)
#pragma unroll
                for (int r = 0; r < 4; ++r) {
                    const int rl = wm + ti2 * 16 + q * 4 + r;
                    const int cl = wn + tj2 * 16 + lrow;
                    dst[rl * 128 + cl] = f2bf(acc[ti2][tj2][r]);
                }
    } else {
        float* G = mat ? Bslab : Aslab;
#pragma unroll
        for (int ti2 = 0; ti2 < 4; ++ti2)
#pragma unroll
            for (int tj2 = 0; tj2 < 4; ++tj2)
#pragma unroll
                for (int r = 0; r < 4; ++r) {
                    const int row = m0 + wm + ti2 * 16 + q * 4 + r;
                    const int col = n0 + wn + tj2 * 16 + lrow;
                    atomicAdd(&G[row * DIMS + col], acc[ti2][tj2][r]);
                }
    }
}

// ============ pass2 (bf16 slabs) + fused tiny finalize (last block of 80) ============
// 80 blocks x 256; each thread owns 8 consecutive elems of one tile. The last
// block to finish reduces the 80 float4 partials (1.3 KB -> ~1 us tail).
__global__ __launch_bounds__(256) void pass2_packed(
    const u16* __restrict__ slabs, const float* __restrict__ diagPart,
    float4* __restrict__ partials, int* __restrict__ cnt, float* __restrict__ out,
    int nsplit)
{
    const int tid = threadIdx.x;
    const int g   = blockIdx.x * 256 + tid;        // 0..20479
    const int p   = g >> 11;                       // tile pair 0..9
    const int e8  = (g & 2047) * 8;
    const float wp = ((p == 0) | (p == 4) | (p == 7) | (p == 9)) ? 1.f : 2.f;

    float a[8] = {}, b[8] = {};
    for (int sb = 0; sb < nsplit; sb += 8) {
        u16x8 va[8], vb[8];
#pragma unroll
        for (int i = 0; i < 8; ++i) {
            va[i] = *(const u16x8*)&slabs[((size_t)((sb + i) * 2 + 0) * 10 + p) * 16384 + e8];
            vb[i] = *(const u16x8*)&slabs[((size_t)((sb + i) * 2 + 1) * 10 + p) * 16384 + e8];
        }
#pragma unroll
        for (int i = 0; i < 8; ++i)
#pragma unroll
            for (int j = 0; j < 8; ++j) {
                a[j] += bf2f(va[i][j]);
                b[j] += bf2f(vb[i][j]);
            }
    }
    float sS = 0.f;
#pragma unroll
    for (int j = 0; j < 8; ++j) sS += a[j] * b[j];
    sS *= wp;

    float sD = 0.f, sD2 = 0.f;
    if (g < N_ROWS) {
        float d = 0.f;
#pragma unroll
        for (int dt = 0; dt < 8; ++dt) d += diagPart[dt * N_ROWS + g];
        sD = d; sD2 = d * d;
    }

    for (int off = 32; off; off >>= 1) {
        sS  += __shfl_xor(sS,  off);
        sD  += __shfl_xor(sD,  off);
        sD2 += __shfl_xor(sD2, off);
    }
    __shared__ float red[3][4];
    const int w = tid >> 6, L = tid & 63;
    if (L == 0) { red[0][w] = sS; red[1][w] = sD; red[2][w] = sD2; }
    __syncthreads();

    __shared__ int sflag;
    if (tid == 0) {
        partials[blockIdx.x] = make_float4(
            red[0][0] + red[0][1] + red[0][2] + red[0][3],
            red[1][0] + red[1][1] + red[1][2] + red[1][3],
            red[2][0] + red[2][1] + red[2][2] + red[2][3], 0.f);
        __threadfence();                       // release partials
        sflag = (atomicAdd(&cnt[0], 1) == 79);
    }
    __syncthreads();
    if (!sflag) return;
    __threadfence();                           // acquire

    float fS = 0.f, fD = 0.f, fD2 = 0.f;
    if (tid < 80) {
        float4 v = partials[tid];
        fS = v.x; fD = v.y; fD2 = v.z;
    }
    for (int off = 32; off; off >>= 1) {
        fS  += __shfl_xor(fS,  off);
        fD  += __shfl_xor(fD,  off);
        fD2 += __shfl_xor(fD2, off);
    }
    if (L == 0) { red[0][w] = fS; red[1][w] = fD; red[2][w] = fD2; }
    __syncthreads();
    if (tid == 0) {
        const double S   = (double)(red[0][0] + red[0][1] + red[0][2] + red[0][3]);
        const double ds  = (double)(red[1][0] + red[1][1] + red[1][2] + red[1][3]);
        const double dsq = (double)(red[2][0] + red[2][1] + red[2][2] + red[2][3]);
        const double loss =
            (S - dsq) / ((double)N_ROWS * (double)(N_ROWS - 1)) - 2.0 * ds / (double)N_ROWS;
        out[0] = (float)loss;
    }
}

// ============ pass2 for atomic-slab tier (fp32 slabs + diagPart) ============
__global__ __launch_bounds__(256) void pass2_sym(
    const float* __restrict__ Aslab, const float* __restrict__ Bslab,
    const float* __restrict__ diagPart, float4* __restrict__ partials)
{
    const int tid = threadIdx.x;
    const int g   = blockIdx.x * 256 + tid;        // 0..20479
    float sS = 0.f, sD = 0.f, sD2 = 0.f;
    for (int e = g; e < DIMS * DIMS; e += 20480) {
        const int r = e >> 9, c = e & 511;
        const float w = ((r >> 7) == (c >> 7)) ? 1.f : 2.f;
        sS += w * Aslab[e] * Bslab[e];
    }
    if (g < N_ROWS) {
        float d = 0.f;
#pragma unroll
        for (int dt = 0; dt < 8; ++dt) d += diagPart[dt * N_ROWS + g];
        sD = d; sD2 = d * d;
    }
    for (int off = 32; off; off >>= 1) {
        sS  += __shfl_xor(sS,  off);
        sD  += __shfl_xor(sD,  off);
        sD2 += __shfl_xor(sD2, off);
    }
    __shared__ float red[3][4];
    if ((tid & 63) == 0) {
        red[0][tid >> 6] = sS; red[1][tid >> 6] = sD; red[2][tid >> 6] = sD2;
    }
    __syncthreads();
    if (tid == 0)
        partials[blockIdx.x] = make_float4(
            red[0][0] + red[0][1] + red[0][2] + red[0][3],
            red[1][0] + red[1][1] + red[1][2] + red[1][3],
            red[2][0] + red[2][1] + red[2][2] + red[2][3], 0.f);
}

__global__ void finalize_partials(const float4* __restrict__ partials, int nb,
                                  float* __restrict__ out)
{
    const int tid = threadIdx.x;   // 64 threads
    float sS = 0.f, sD = 0.f, sD2 = 0.f;
    for (int i = tid; i < nb; i += 64) {
        float4 v = partials[i];
        sS += v.x; sD += v.y; sD2 += v.z;
    }
    for (int off = 32; off; off >>= 1) {
        sS  += __shfl_xor(sS,  off);
        sD  += __shfl_xor(sD,  off);
        sD2 += __shfl_xor(sD2, off);
    }
    if (tid == 0) {
        const double offd = (double)sS - (double)sD2;
        const double loss =
            offd / ((double)N_ROWS * (double)(N_ROWS - 1)) - 2.0 * (double)sD / (double)N_ROWS;
        out[0] = (float)loss;
    }
}

// ============ fp32 vector fallback (round-1, proven) ============
#define TILE   64
#define KSPLIT 8
#define KCHUNK (N_ROWS / KSPLIT)
#define KB     16
__global__ __launch_bounds__(NT) void syrk_kernel(
    const float* __restrict__ X, const float* __restrict__ Y,
    float* __restrict__ Abase, float* __restrict__ Bbase, int useSlabs)
{
    const int tid = threadIdx.x;
    const int ta  = blockIdx.x >> 3;
    const int tb  = blockIdx.x & 7;
    const int s   = blockIdx.y;
    const int ca  = tid & 15;
    const int cb  = tid >> 4;

    __shared__ float4 sXA[KB * 16];
    __shared__ float4 sXB[KB * 16];
    __shared__ float4 sYA[KB * 16];
    __shared__ float4 sYB[KB * 16];

    const float4* Xv = (const float4*)X;
    const float4* Yv = (const float4*)Y;

    float aA[4][4] = {};
    float aB[4][4] = {};

    const int r0     = s * KCHUNK;
    const int rowOfT = tid >> 4;
    const int colOfT = tid & 15;

    for (int it = 0; it < KCHUNK / KB; ++it) {
        const int row  = r0 + it * KB + rowOfT;
        const int base = row * (DIMS / 4);
        __syncthreads();
        sXA[tid] = Xv[base + ta * 16 + colOfT];
        sXB[tid] = Xv[base + tb * 16 + colOfT];
        sYA[tid] = Yv[base + ta * 16 + colOfT];
        sYB[tid] = Yv[base + tb * 16 + colOfT];
        __syncthreads();
#pragma unroll
        for (int k = 0; k < KB; ++k) {
            float4 xa4 = sXA[k * 16 + ca];
            float4 xb4 = sXB[k * 16 + cb];
            float4 ya4 = sYA[k * 16 + ca];
            float4 yb4 = sYB[k * 16 + cb];
            float xa[4] = {xa4.x, xa4.y, xa4.z, xa4.w};
            float xb[4] = {xb4.x, xb4.y, xb4.z, xb4.w};
            float ya[4] = {ya4.x, ya4.y, ya4.z, ya4.w};
            float yb[4] = {yb4.x, yb4.y, yb4.z, yb4.w};
#pragma unroll
            for (int i = 0; i < 4; ++i)
#pragma unroll
                for (int j = 0; j < 4; ++j) {
                    aA[i][j] = fmaf(xa[i], xb[j], aA[i][j]);
                    aB[i][j] = fmaf(ya[i], yb[j], aB[i][j]);
                }
        }
    }

    const size_t slabElems = (size_t)DIMS * DIMS;
    float* Adst = Abase + (useSlabs ? (size_t)s * slabElems : 0);
    float* Bdst = Bbase + (useSlabs ? (size_t)s * slabElems : 0);

#pragma unroll
    for (int i = 0; i < 4; ++i) {
        const int    ag    = ta * TILE + ca * 4 + i;
        const int    cbase = tb * TILE + cb * 4;
        const size_t idx   = (size_t)ag * DIMS + cbase;
        if (useSlabs) {
            *(float4*)(Adst + idx) = make_float4(aA[i][0], aA[i][1], aA[i][2], aA[i][3]);
            *(float4*)(Bdst + idx) = make_float4(aB[i][0], aB[i][1], aB[i][2], aB[i][3]);
        } else {
#pragma unroll
            for (int j = 0; j < 4; ++j) {
                atomicAdd(Adst + idx + j, aA[i][j]);
                atomicAdd(Bdst + idx + j, aB[i][j]);
            }
        }
    }
}

__global__ __launch_bounds__(256) void diag_kernel(
    const float* __restrict__ X, const float* __restrict__ Y,
    float* __restrict__ scal)
{
    const int tid  = threadIdx.x;
    const int lane = tid & 63;
    const int wave = blockIdx.x * 4 + (tid >> 6);
    const float4* Xv = (const float4*)X;
    const float4* Yv = (const float4*)Y;

    float dsum = 0.f, dsq = 0.f;
    for (int r = 0; r < 8; ++r) {
        const int row  = wave * 8 + r;
        const int base = row * (DIMS / 4) + lane * 2;
        float4 x0 = Xv[base], x1 = Xv[base + 1];
        float4 y0 = Yv[base], y1 = Yv[base + 1];
        float v = x0.x * y0.x + x0.y * y0.y + x0.z * y0.z + x0.w * y0.w
                + x1.x * y1.x + x1.y * y1.y + x1.z * y1.z + x1.w * y1.w;
        for (int off = 32; off; off >>= 1) v += __shfl_xor(v, off);
        if (lane == 0) { dsum += v; dsq += v * v; }
    }
    if (lane == 0) {
        atomicAdd(scal + 0, dsum);
        atomicAdd(scal + 1, dsq);
    }
}

__global__ __launch_bounds__(256) void pass2_kernel(
    const float* __restrict__ Abase, const float* __restrict__ Bbase,
    float* __restrict__ scal, int nslab)
{
    const int tid = threadIdx.x;
    const int g   = blockIdx.x * 256 + tid;
    const size_t slabElems = (size_t)DIMS * DIMS;
    float local = 0.f;
    for (int e = g; e < (int)slabElems; e += 65536) {
        float a = 0.f, b = 0.f;
        for (int s2 = 0; s2 < nslab; ++s2) {
            a += Abase[(size_t)s2 * slabElems + e];
            b += Bbase[(size_t)s2 * slabElems + e];
        }
        local += a * b;
    }
    for (int off = 32; off; off >>= 1) local += __shfl_xor(local, off);
    __shared__ float red[4];
    if ((tid & 63) == 0) red[tid >> 6] = local;
    __syncthreads();
    if (tid == 0) atomicAdd(scal + 2, red[0] + red[1] + red[2] + red[3]);
}

__global__ void finalize_kernel(const float* __restrict__ scal,
                                float* __restrict__ out)
{
    if (threadIdx.x == 0 && blockIdx.x == 0) {
        const double S   = (double)scal[2];
        const double dsq = (double)scal[1];
        const double ds  = (double)scal[0];
        const double off = S - dsq;
        const double loss =
            off / ((double)N_ROWS * (double)(N_ROWS - 1)) - 2.0 * ds / (double)N_ROWS;
        out[0] = (float)loss;
    }
}

extern "C" void kernel_launch(void* const* d_in, const int* in_sizes, int n_in,
                              void* d_out, int out_size, void* d_ws, size_t ws_size,
                              hipStream_t stream)
{
    const float* X = (const float*)d_in[0];
    const float* Y = (const float*)d_in[1];
    float* out = (float*)d_out;
    float* wsf = (float*)d_ws;

    const size_t trElems = (size_t)DIMS * N_ROWS;             // 4,194,304 bf16/matrix
    // Layout: [cnt 16 int | pad | partials 80 float4 | pad to 448 f | diagPart 8x8192 f | Xh | Yh | slabs]
    const size_t hdrF   = 448;           // 16 (cnt) + 64 pad + 320 (partials) + pad
    const size_t diagF  = 8 * N_ROWS;
    const size_t coreB  = (hdrF + diagF) * sizeof(float) + 2 * trElems * sizeof(u16);
    auto slabB = [](int ns) { return (size_t)ns * 2 * 10 * 16384 * sizeof(u16); };

    int*    cnt      = (int*)wsf;
    float4* partials = (float4*)(wsf + 64);
    float*  diagPart = wsf + hdrF;
    u16* Xh = (u16*)(diagPart + diagF);
    u16* Yh = Xh + trElems;

    int nsplit = 0;
    if      (ws_size >= coreB + slabB(32)) nsplit = 32;
    else if (ws_size >= coreB + slabB(16)) nsplit = 16;

    if (nsplit) {
        // primary: 3 dispatches, no memsets, no cross-XCD atomics on hot data
        u16* slabs = (u16*)(Yh + trElems);
        convert_diag<<<1024, NT, 0, stream>>>(X, Y, Xh, Yh, diagPart, cnt);
        syrk_bf16<<<dim3(nsplit, 10, 2), NT, 0, stream>>>(
            Xh, Yh, slabs, nullptr, nullptr, N_ROWS / nsplit, 0);
        pass2_packed<<<80, 256, 0, stream>>>(slabs, diagPart, partials, cnt, out, nsplit);
    } else if (ws_size >= coreB + 2 * (size_t)DIMS * DIMS * sizeof(float)) {
        // atomic tier: fp32 A/B slabs
        float* Aslab = (float*)(Yh + trElems);
        float* Bslab = Aslab + DIMS * DIMS;
        float4* part2 = (float4*)(Bslab + DIMS * DIMS);
        hipMemsetAsync(Aslab, 0, 2 * (size_t)DIMS * DIMS * sizeof(float), stream);
        convert_diag<<<1024, NT, 0, stream>>>(X, Y, Xh, Yh, diagPart, cnt);
        syrk_bf16<<<dim3(32, 10, 2), NT, 0, stream>>>(
            Xh, Yh, nullptr, Aslab, Bslab, N_ROWS / 32, 1);
        pass2_sym<<<80, 256, 0, stream>>>(Aslab, Bslab, diagPart, part2);
        finalize_partials<<<1, 64, 0, stream>>>(part2, 80, out);
    } else {
        // fp32 vector fallback (round-1 path)
        const size_t slabElems = (size_t)DIMS * DIMS;
        const size_t hdr = 64;
        const bool slabs2 = ws_size >= (hdr + 16 * slabElems) * sizeof(float);
        const int  nslab = slabs2 ? KSPLIT : 1;
        float* Abase = wsf + hdr;
        float* Bbase = Abase + (size_t)nslab * slabElems;

        hipMemsetAsync(d_ws, 0, hdr * sizeof(float), stream);
        if (!slabs2) hipMemsetAsync(Abase, 0, 2 * slabElems * sizeof(float), stream);

        dim3 sg(64, KSPLIT);
        syrk_kernel<<<sg, NT, 0, stream>>>(X, Y, Abase, Bbase, slabs2 ? 1 : 0);
        diag_kernel<<<256, 256, 0, stream>>>(X, Y, wsf);
        pass2_kernel<<<256, 256, 0, stream>>>(Abase, Bbase, wsf, nslab);
        finalize_kernel<<<1, 64, 0, stream>>>(wsf, out);
    }
}

// Round 8
// 95.842 us; speedup vs baseline: 2.3967x; 1.0402x over previous
//
#include <hip/hip_runtime.h>
#include <cstdint>

#define N_ROWS 8192
#define DIMS   512
#define NT     256

typedef unsigned short u16;
typedef unsigned char  u8;
typedef __attribute__((ext_vector_type(8))) short s8v;            // 8 bf16 MFMA A/B frag
typedef __attribute__((ext_vector_type(4))) float f4v;            // MFMA C/D frag
typedef __attribute__((ext_vector_type(8))) unsigned short u16x8;

__device__ __forceinline__ u16 f2bf(float f) {
    unsigned u = __float_as_uint(f);
    unsigned r = (u + 0x7fff + ((u >> 16) & 1)) >> 16;
    return (u16)r;
}
__device__ __forceinline__ float bf2f(u16 h) { return __uint_as_float(((unsigned)h) << 16); }

__device__ __forceinline__ void gl16(const void* g, void* l) {
    auto gp = (const __attribute__((address_space(1))) unsigned int*)(uintptr_t)g;
    auto lp = (__attribute__((address_space(3))) unsigned int*)(uintptr_t)l;
    __builtin_amdgcn_global_load_lds(gp, lp, 16, 0, 0);
}

// pack 4 floats -> 4 fp8 e4m3 (OCP) via v_cvt_pk_fp8_f32 (RNE)
__device__ __forceinline__ unsigned pk4fp8(float a, float b, float c, float d) {
    int r = 0;
    r = __builtin_amdgcn_cvt_pk_fp8_f32(a, b, r, false);   // bytes 0-1
    r = __builtin_amdgcn_cvt_pk_fp8_f32(c, d, r, true);    // bytes 2-3
    return (unsigned)r;
}

// ============ convert + transpose -> fp8 [512][8192] + diag partials + cnt zero ============
// grid: 1024 blocks (nt 0..127, dt 0..7).
__global__ __launch_bounds__(NT) void convert_fp8(
    const float* __restrict__ X, const float* __restrict__ Y,
    u8* __restrict__ Xq, u8* __restrict__ Yq,
    float* __restrict__ diagPart, int* __restrict__ cnt)
{
    const int b  = blockIdx.x;
    const int nt = b & 127;
    const int dt = b >> 7;
    const int tid = threadIdx.x;

    if (b == 0 && tid < 16) cnt[tid] = 0;

    __shared__ float tx[64][65];
    __shared__ float ty[64][65];

    const int c4 = tid & 15, rr = tid >> 4;
#pragma unroll
    for (int rp = 0; rp < 4; ++rp) {
        const int row = rp * 16 + rr;
        const size_t gbase = (size_t)(nt * 64 + row) * DIMS + dt * 64 + c4 * 4;
        float4 vx = *(const float4*)&X[gbase];
        float4 vy = *(const float4*)&Y[gbase];
        tx[row][c4 * 4 + 0] = vx.x; tx[row][c4 * 4 + 1] = vx.y;
        tx[row][c4 * 4 + 2] = vx.z; tx[row][c4 * 4 + 3] = vx.w;
        ty[row][c4 * 4 + 0] = vy.x; ty[row][c4 * 4 + 1] = vy.y;
        ty[row][c4 * 4 + 2] = vy.z; ty[row][c4 * 4 + 3] = vy.w;
        float d = vx.x * vy.x + vx.y * vy.y + vx.z * vy.z + vx.w * vy.w;
        d += __shfl_xor(d, 1); d += __shfl_xor(d, 2);
        d += __shfl_xor(d, 4); d += __shfl_xor(d, 8);
        if (c4 == 0) diagPart[dt * N_ROWS + nt * 64 + row] = d;
    }
    __syncthreads();

    const int d = tid >> 2, ns = (tid & 3) * 16;
    const size_t ob = (size_t)(dt * 64 + d) * N_ROWS + nt * 64 + ns;
#pragma unroll
    for (int mat = 0; mat < 2; ++mat) {
        float (*tp)[65] = mat ? ty : tx;
        u8* Oq = mat ? Yq : Xq;
        float v[16];
#pragma unroll
        for (int i = 0; i < 16; ++i) v[i] = tp[ns + i][d];
        uint4 w;
        w.x = pk4fp8(v[0],  v[1],  v[2],  v[3]);
        w.y = pk4fp8(v[4],  v[5],  v[6],  v[7]);
        w.z = pk4fp8(v[8],  v[9],  v[10], v[11]);
        w.w = pk4fp8(v[12], v[13], v[14], v[15]);
        *(uint4*)&Oq[ob] = w;
    }
}

// ============ symmetric fp8 syrk, BK=64 double-buffer, 32 KB LDS ============
// grid (nsplit, 10, 2). 4 blocks/CU resident. Per wave 64x64 = 4x4 16x16x32
// fp8 tiles, 32 MFMA / BK-64 iter. LDS row = 64 B (4 x 16B chunks), phys
// chunk = logical ^ ((row>>1)&3) -> b64 frag reads conflict-free.
// Epilogue: bf16 store to private slab slot.
__global__ __launch_bounds__(NT, 4) void syrk_fp8(
    const u8* __restrict__ Xq, const u8* __restrict__ Yq,
    u16* __restrict__ slabs, int kchunk)
{
    __shared__ u8 smem[2 * 2 * 8192];   // [stage][stripe][128 rows * 64 B] = 32 KB

    const int tid = threadIdx.x;
    const int s = blockIdx.x, p = blockIdx.y, mat = blockIdx.z;
    const int ti_t[10] = {0,0,0,0,1,1,1,2,2,3};
    const int tj_t[10] = {0,1,2,3,1,2,3,2,3,3};
    const int m0 = ti_t[p] * 128, n0 = tj_t[p] * 128;
    const u8* Tq = mat ? Yq : Xq;

    const int w = tid >> 6, L = tid & 63;
    const int wm = (w >> 1) * 64, wn = (w & 1) * 64;
    const int lrow = L & 15, q = L >> 4;
    const int qh = q >> 1, ql = q & 1;

    f4v acc[4][4];
#pragma unroll
    for (int i = 0; i < 4; ++i)
#pragma unroll
        for (int j = 0; j < 4; ++j)
            acc[i][j] = (f4v){0.f, 0.f, 0.f, 0.f};

    const int kk0 = s * kchunk;
    const int nIter = kchunk / 64;

    // stage loader: stripe = 128 rows x 64 fp8; 512 16B-slots, 2 rounds/stripe.
    // LDS dst is lane-forced (slot*16); source k-chunk picked so that phys
    // chunk (slot&3) holds logical chunk (slot&3)^((row>>1)&3).
    auto loadStage = [&](int buf, int kb) {
        u8* dA = smem + buf * 16384;
        u8* dB = dA + 8192;
#pragma unroll
        for (int j = 0; j < 2; ++j) {
            const int slot = j * 256 + tid;
            const int row  = slot >> 2;
            const int c    = (slot & 3) ^ ((row >> 1) & 3);
            gl16(Tq + (size_t)(m0 + row) * N_ROWS + kb + c * 16, dA + slot * 16);
            gl16(Tq + (size_t)(n0 + row) * N_ROWS + kb + c * 16, dB + slot * 16);
        }
    };

    loadStage(0, kk0);

    for (int it = 0; it < nIter; ++it) {
        __syncthreads();                 // drains stage-it gl16s, syncs block
        if (it + 1 < nIter) loadStage((it + 1) & 1, kk0 + (it + 1) * 64);

        const u8* SA = smem + (it & 1) * 16384;
        const u8* SB = SA + 8192;
#pragma unroll
        for (int s2 = 0; s2 < 2; ++s2) {
            long a[4], b[4];
#pragma unroll
            for (int t = 0; t < 4; ++t) {
                const int rowA = wm + t * 16 + lrow;
                const int rowB = wn + t * 16 + lrow;
                const int cA = (s2 * 2 + qh) ^ ((rowA >> 1) & 3);
                const int cB = (s2 * 2 + qh) ^ ((rowB >> 1) & 3);
                a[t] = *(const long*)&SA[rowA * 64 + cA * 16 + ql * 8];
                b[t] = *(const long*)&SB[rowB * 64 + cB * 16 + ql * 8];
            }
#pragma unroll
            for (int ti2 = 0; ti2 < 4; ++ti2)
#pragma unroll
                for (int tj2 = 0; tj2 < 4; ++tj2)
                    acc[ti2][tj2] = __builtin_amdgcn_mfma_f32_16x16x32_fp8_fp8(
                        a[ti2], b[tj2], acc[ti2][tj2], 0, 0, 0);
        }
    }

    u16* dst = slabs + ((size_t)(s * 2 + mat) * 10 + p) * 16384;
#pragma unroll
    for (int ti2 = 0; ti2 < 4; ++ti2)
#pragma unroll
        for (int tj2 = 0; tj2 < 4; ++tj2)
#pragma unroll
            for (int r = 0; r < 4; ++r) {
                const int rl = wm + ti2 * 16 + q * 4 + r;
                const int cl = wn + tj2 * 16 + lrow;
                dst[rl * 128 + cl] = f2bf(acc[ti2][tj2][r]);
            }
}

// ============ pass2 (bf16 slabs) + fused tiny finalize (last block of 80) ============
__global__ __launch_bounds__(256) void pass2_packed(
    const u16* __restrict__ slabs, const float* __restrict__ diagPart,
    float4* __restrict__ partials, int* __restrict__ cnt, float* __restrict__ out,
    int nsplit)
{
    const int tid = threadIdx.x;
    const int g   = blockIdx.x * 256 + tid;        // 0..20479
    const int p   = g >> 11;                       // tile pair 0..9
    const int e8  = (g & 2047) * 8;
    const float wp = ((p == 0) | (p == 4) | (p == 7) | (p == 9)) ? 1.f : 2.f;

    float a[8] = {}, b[8] = {};
    for (int sb = 0; sb < nsplit; sb += 8) {
        u16x8 va[8], vb[8];
#pragma unroll
        for (int i = 0; i < 8; ++i) {
            va[i] = *(const u16x8*)&slabs[((size_t)((sb + i) * 2 + 0) * 10 + p) * 16384 + e8];
            vb[i] = *(const u16x8*)&slabs[((size_t)((sb + i) * 2 + 1) * 10 + p) * 16384 + e8];
        }
#pragma unroll
        for (int i = 0; i < 8; ++i)
#pragma unroll
            for (int j = 0; j < 8; ++j) {
                a[j] += bf2f(va[i][j]);
                b[j] += bf2f(vb[i][j]);
            }
    }
    float sS = 0.f;
#pragma unroll
    for (int j = 0; j < 8; ++j) sS += a[j] * b[j];
    sS *= wp;

    float sD = 0.f, sD2 = 0.f;
    if (g < N_ROWS) {
        float d = 0.f;
#pragma unroll
        for (int dt = 0; dt < 8; ++dt) d += diagPart[dt * N_ROWS + g];
        sD = d; sD2 = d * d;
    }

    for (int off = 32; off; off >>= 1) {
        sS  += __shfl_xor(sS,  off);
        sD  += __shfl_xor(sD,  off);
        sD2 += __shfl_xor(sD2, off);
    }
    __shared__ float red[3][4];
    const int w = tid >> 6, L = tid & 63;
    if (L == 0) { red[0][w] = sS; red[1][w] = sD; red[2][w] = sD2; }
    __syncthreads();

    __shared__ int sflag;
    if (tid == 0) {
        partials[blockIdx.x] = make_float4(
            red[0][0] + red[0][1] + red[0][2] + red[0][3],
            red[1][0] + red[1][1] + red[1][2] + red[1][3],
            red[2][0] + red[2][1] + red[2][2] + red[2][3], 0.f);
        __threadfence();                       // release partials
        sflag = (atomicAdd(&cnt[0], 1) == 79);
    }
    __syncthreads();
    if (!sflag) return;
    __threadfence();                           // acquire

    float fS = 0.f, fD = 0.f, fD2 = 0.f;
    if (tid < 80) {
        float4 v = partials[tid];
        fS = v.x; fD = v.y; fD2 = v.z;
    }
    for (int off = 32; off; off >>= 1) {
        fS  += __shfl_xor(fS,  off);
        fD  += __shfl_xor(fD,  off);
        fD2 += __shfl_xor(fD2, off);
    }
    if (L == 0) { red[0][w] = fS; red[1][w] = fD; red[2][w] = fD2; }
    __syncthreads();
    if (tid == 0) {
        const double S   = (double)(red[0][0] + red[0][1] + red[0][2] + red[0][3]);
        const double ds  = (double)(red[1][0] + red[1][1] + red[1][2] + red[1][3]);
        const double dsq = (double)(red[2][0] + red[2][1] + red[2][2] + red[2][3]);
        const double loss =
            (S - dsq) / ((double)N_ROWS * (double)(N_ROWS - 1)) - 2.0 * ds / (double)N_ROWS;
        out[0] = (float)loss;
    }
}

// ====================== fallback tiers (R7-proven, unchanged) ======================

__global__ __launch_bounds__(NT) void convert_diag(
    const float* __restrict__ X, const float* __restrict__ Y,
    u16* __restrict__ Xh, u16* __restrict__ Yh,
    float* __restrict__ diagPart, int* __restrict__ cnt)
{
    const int b  = blockIdx.x;
    const int nt = b & 127;
    const int dt = b >> 7;
    const int tid = threadIdx.x;

    if (b == 0 && tid < 16) cnt[tid] = 0;

    __shared__ float tx[64][65];
    __shared__ float ty[64][65];

    const int c4 = tid & 15, rr = tid >> 4;
#pragma unroll
    for (int rp = 0; rp < 4; ++rp) {
        const int row = rp * 16 + rr;
        const size_t gbase = (size_t)(nt * 64 + row) * DIMS + dt * 64 + c4 * 4;
        float4 vx = *(const float4*)&X[gbase];
        float4 vy = *(const float4*)&Y[gbase];
        tx[row][c4 * 4 + 0] = vx.x; tx[row][c4 * 4 + 1] = vx.y;
        tx[row][c4 * 4 + 2] = vx.z; tx[row][c4 * 4 + 3] = vx.w;
        ty[row][c4 * 4 + 0] = vy.x; ty[row][c4 * 4 + 1] = vy.y;
        ty[row][c4 * 4 + 2] = vy.z; ty[row][c4 * 4 + 3] = vy.w;
        float d = vx.x * vy.x + vx.y * vy.y + vx.z * vy.z + vx.w * vy.w;
        d += __shfl_xor(d, 1); d += __shfl_xor(d, 2);
        d += __shfl_xor(d, 4); d += __shfl_xor(d, 8);
        if (c4 == 0) diagPart[dt * N_ROWS + nt * 64 + row] = d;
    }
    __syncthreads();

    const int d = tid >> 2, ns = (tid & 3) * 16;
    const size_t ob = (size_t)(dt * 64 + d) * N_ROWS + nt * 64 + ns;
#pragma unroll
    for (int mat = 0; mat < 2; ++mat) {
        float (*tp)[65] = mat ? ty : tx;
        u16* Oh = mat ? Yh : Xh;
        u16x8 h0, h1;
#pragma unroll
        for (int i = 0; i < 8; ++i) {
            h0[i] = f2bf(tp[ns + i][d]);
            h1[i] = f2bf(tp[ns + 8 + i][d]);
        }
        *(u16x8*)&Oh[ob]     = h0;
        *(u16x8*)&Oh[ob + 8] = h1;
    }
}

__global__ __launch_bounds__(NT, 4) void syrk_bf16(
    const u16* __restrict__ Xh, const u16* __restrict__ Yh,
    float* __restrict__ Aslab, float* __restrict__ Bslab, int kchunk)
{
    __shared__ u16 smem[2 * 2 * 4096];   // 32 KB

    const int tid = threadIdx.x;
    const int s = blockIdx.x, p = blockIdx.y, mat = blockIdx.z;
    const int ti_t[10] = {0,0,0,0,1,1,1,2,2,3};
    const int tj_t[10] = {0,1,2,3,1,2,3,2,3,3};
    const int m0 = ti_t[p] * 128, n0 = tj_t[p] * 128;
    const u16* Th = mat ? Yh : Xh;

    const int w = tid >> 6, L = tid & 63;
    const int wm = (w >> 1) * 64, wn = (w & 1) * 64;
    const int lrow = L & 15, q = L >> 4;

    f4v acc[4][4];
#pragma unroll
    for (int i = 0; i < 4; ++i)
#pragma unroll
        for (int j = 0; j < 4; ++j)
            acc[i][j] = (f4v){0.f, 0.f, 0.f, 0.f};

    const int kk0 = s * kchunk;
    const int nIter = kchunk / 32;

    auto loadStage = [&](int buf, int kb) {
        u16* dA = smem + buf * 8192;
        u16* dB = dA + 4096;
#pragma unroll
        for (int j = 0; j < 2; ++j) {
            const int slot = j * 256 + tid;
            const int row  = slot >> 2;
            const int c    = (slot & 3) ^ ((row >> 1) & 3);
            gl16(Th + (size_t)(m0 + row) * N_ROWS + kb + c * 8, dA + slot * 8);
            gl16(Th + (size_t)(n0 + row) * N_ROWS + kb + c * 8, dB + slot * 8);
        }
    };

    loadStage(0, kk0);

    for (int it = 0; it < nIter; ++it) {
        __syncthreads();
        if (it + 1 < nIter) loadStage((it + 1) & 1, kk0 + (it + 1) * 32);

        const u16* SA = smem + (it & 1) * 8192;
        const u16* SB = SA + 4096;
        s8v a[4], b[4];
#pragma unroll
        for (int t = 0; t < 4; ++t) {
            const int rowA = wm + t * 16 + lrow;
            const int rowB = wn + t * 16 + lrow;
            const int pA = q ^ ((rowA >> 1) & 3);
            const int pB = q ^ ((rowB >> 1) & 3);
            a[t] = *(const s8v*)&SA[rowA * 32 + pA * 8];
            b[t] = *(const s8v*)&SB[rowB * 32 + pB * 8];
        }
#pragma unroll
        for (int ti2 = 0; ti2 < 4; ++ti2)
#pragma unroll
            for (int tj2 = 0; tj2 < 4; ++tj2)
                acc[ti2][tj2] = __builtin_amdgcn_mfma_f32_16x16x32_bf16(
                    a[ti2], b[tj2], acc[ti2][tj2], 0, 0, 0);
    }

    float* G = mat ? Bslab : Aslab;
#pragma unroll
    for (int ti2 = 0; ti2 < 4; ++ti2)
#pragma unroll
        for (int tj2 = 0; tj2 < 4; ++tj2)
#pragma unroll
            for (int r = 0; r < 4; ++r) {
                const int row = m0 + wm + ti2 * 16 + q * 4 + r;
                const int col = n0 + wn + tj2 * 16 + lrow;
                atomicAdd(&G[row * DIMS + col], acc[ti2][tj2][r]);
            }
}

__global__ __launch_bounds__(256) void pass2_sym(
    const float* __restrict__ Aslab, const float* __restrict__ Bslab,
    const float* __restrict__ diagPart, float4* __restrict__ partials)
{
    const int tid = threadIdx.x;
    const int g   = blockIdx.x * 256 + tid;
    float sS = 0.f, sD = 0.f, sD2 = 0.f;
    for (int e = g; e < DIMS * DIMS; e += 20480) {
        const int r = e >> 9, c = e & 511;
        const float w = ((r >> 7) == (c >> 7)) ? 1.f : 2.f;
        sS += w * Aslab[e] * Bslab[e];
    }
    if (g < N_ROWS) {
        float d = 0.f;
#pragma unroll
        for (int dt = 0; dt < 8; ++dt) d += diagPart[dt * N_ROWS + g];
        sD = d; sD2 = d * d;
    }
    for (int off = 32; off; off >>= 1) {
        sS  += __shfl_xor(sS,  off);
        sD  += __shfl_xor(sD,  off);
        sD2 += __shfl_xor(sD2, off);
    }
    __shared__ float red[3][4];
    if ((tid & 63) == 0) {
        red[0][tid >> 6] = sS; red[1][tid >> 6] = sD; red[2][tid >> 6] = sD2;
    }
    __syncthreads();
    if (tid == 0)
        partials[blockIdx.x] = make_float4(
            red[0][0] + red[0][1] + red[0][2] + red[0][3],
            red[1][0] + red[1][1] + red[1][2] + red[1][3],
            red[2][0] + red[2][1] + red[2][2] + red[2][3], 0.f);
}

__global__ void finalize_partials(const float4* __restrict__ partials, int nb,
                                  float* __restrict__ out)
{
    const int tid = threadIdx.x;
    float sS = 0.f, sD = 0.f, sD2 = 0.f;
    for (int i = tid; i < nb; i += 64) {
        float4 v = partials[i];
        sS += v.x; sD += v.y; sD2 += v.z;
    }
    for (int off = 32; off; off >>= 1) {
        sS  += __shfl_xor(sS,  off);
        sD  += __shfl_xor(sD,  off);
        sD2 += __shfl_xor(sD2, off);
    }
    if (tid == 0) {
        const double offd = (double)sS - (double)sD2;
        const double loss =
            offd / ((double)N_ROWS * (double)(N_ROWS - 1)) - 2.0 * (double)sD / (double)N_ROWS;
        out[0] = (float)loss;
    }
}

#define TILE   64
#define KSPLIT 8
#define KCHUNK (N_ROWS / KSPLIT)
#define KB     16
__global__ __launch_bounds__(NT) void syrk_kernel(
    const float* __restrict__ X, const float* __restrict__ Y,
    float* __restrict__ Abase, float* __restrict__ Bbase, int useSlabs)
{
    const int tid = threadIdx.x;
    const int ta  = blockIdx.x >> 3;
    const int tb  = blockIdx.x & 7;
    const int s   = blockIdx.y;
    const int ca  = tid & 15;
    const int cb  = tid >> 4;

    __shared__ float4 sXA[KB * 16];
    __shared__ float4 sXB[KB * 16];
    __shared__ float4 sYA[KB * 16];
    __shared__ float4 sYB[KB * 16];

    const float4* Xv = (const float4*)X;
    const float4* Yv = (const float4*)Y;

    float aA[4][4] = {};
    float aB[4][4] = {};

    const int r0     = s * KCHUNK;
    const int rowOfT = tid >> 4;
    const int colOfT = tid & 15;

    for (int it = 0; it < KCHUNK / KB; ++it) {
        const int row  = r0 + it * KB + rowOfT;
        const int base = row * (DIMS / 4);
        __syncthreads();
        sXA[tid] = Xv[base + ta * 16 + colOfT];
        sXB[tid] = Xv[base + tb * 16 + colOfT];
        sYA[tid] = Yv[base + ta * 16 + colOfT];
        sYB[tid] = Yv[base + tb * 16 + colOfT];
        __syncthreads();
#pragma unroll
        for (int k = 0; k < KB; ++k) {
            float4 xa4 = sXA[k * 16 + ca];
            float4 xb4 = sXB[k * 16 + cb];
            float4 ya4 = sYA[k * 16 + ca];
            float4 yb4 = sYB[k * 16 + cb];
            float xa[4] = {xa4.x, xa4.y, xa4.z, xa4.w};
            float xb[4] = {xb4.x, xb4.y, xb4.z, xb4.w};
            float ya[4] = {ya4.x, ya4.y, ya4.z, ya4.w};
            float yb[4] = {yb4.x, yb4.y, yb4.z, yb4.w};
#pragma unroll
            for (int i = 0; i < 4; ++i)
#pragma unroll
                for (int j = 0; j < 4; ++j) {
                    aA[i][j] = fmaf(xa[i], xb[j], aA[i][j]);
                    aB[i][j] = fmaf(ya[i], yb[j], aB[i][j]);
                }
        }
    }

    const size_t slabElems = (size_t)DIMS * DIMS;
    float* Adst = Abase + (useSlabs ? (size_t)s * slabElems : 0);
    float* Bdst = Bbase + (useSlabs ? (size_t)s * slabElems : 0);

#pragma unroll
    for (int i = 0; i < 4; ++i) {
        const int    ag    = ta * TILE + ca * 4 + i;
        const int    cbase = tb * TILE + cb * 4;
        const size_t idx   = (size_t)ag * DIMS + cbase;
        if (useSlabs) {
            *(float4*)(Adst + idx) = make_float4(aA[i][0], aA[i][1], aA[i][2], aA[i][3]);
            *(float4*)(Bdst + idx) = make_float4(aB[i][0], aB[i][1], aB[i][2], aB[i][3]);
        } else {
#pragma unroll
            for (int j = 0; j < 4; ++j) {
                atomicAdd(Adst + idx + j, aA[i][j]);
                atomicAdd(Bdst + idx + j, aB[i][j]);
            }
        }
    }
}

__global__ __launch_bounds__(256) void diag_kernel(
    const float* __restrict__ X, const float* __restrict__ Y,
    float* __restrict__ scal)
{
    const int tid  = threadIdx.x;
    const int lane = tid & 63;
    const int wave = blockIdx.x * 4 + (tid >> 6);
    const float4* Xv = (const float4*)X;
    const float4* Yv = (const float4*)Y;

    float dsum = 0.f, dsq = 0.f;
    for (int r = 0; r < 8; ++r) {
        const int row  = wave * 8 + r;
        const int base = row * (DIMS / 4) + lane * 2;
        float4 x0 = Xv[base], x1 = Xv[base + 1];
        float4 y0 = Yv[base], y1 = Yv[base + 1];
        float v = x0.x * y0.x + x0.y * y0.y + x0.z * y0.z + x0.w * y0.w
                + x1.x * y1.x + x1.y * y1.y + x1.z * y1.z + x1.w * y1.w;
        for (int off = 32; off; off >>= 1) v += __shfl_xor(v, off);
        if (lane == 0) { dsum += v; dsq += v * v; }
    }
    if (lane == 0) {
        atomicAdd(scal + 0, dsum);
        atomicAdd(scal + 1, dsq);
    }
}

__global__ __launch_bounds__(256) void pass2_kernel(
    const float* __restrict__ Abase, const float* __restrict__ Bbase,
    float* __restrict__ scal, int nslab)
{
    const int tid = threadIdx.x;
    const int g   = blockIdx.x * 256 + tid;
    const size_t slabElems = (size_t)DIMS * DIMS;
    float local = 0.f;
    for (int e = g; e < (int)slabElems; e += 65536) {
        float a = 0.f, b = 0.f;
        for (int s2 = 0; s2 < nslab; ++s2) {
            a += Abase[(size_t)s2 * slabElems + e];
            b += Bbase[(size_t)s2 * slabElems + e];
        }
        local += a * b;
    }
    for (int off = 32; off; off >>= 1) local += __shfl_xor(local, off);
    __shared__ float red[4];
    if ((tid & 63) == 0) red[tid >> 6] = local;
    __syncthreads();
    if (tid == 0) atomicAdd(scal + 2, red[0] + red[1] + red[2] + red[3]);
}

__global__ void finalize_kernel(const float* __restrict__ scal,
                                float* __restrict__ out)
{
    if (threadIdx.x == 0 && blockIdx.x == 0) {
        const double S   = (double)scal[2];
        const double dsq = (double)scal[1];
        const double ds  = (double)scal[0];
        const double off = S - dsq;
        const double loss =
            off / ((double)N_ROWS * (double)(N_ROWS - 1)) - 2.0 * ds / (double)N_ROWS;
        out[0] = (float)loss;
    }
}

extern "C" void kernel_launch(void* const* d_in, const int* in_sizes, int n_in,
                              void* d_out, int out_size, void* d_ws, size_t ws_size,
                              hipStream_t stream)
{
    const float* X = (const float*)d_in[0];
    const float* Y = (const float*)d_in[1];
    float* out = (float*)d_out;
    float* wsf = (float*)d_ws;

    const size_t trElems = (size_t)DIMS * N_ROWS;             // 4,194,304 elems/matrix
    const size_t hdrF   = 448;           // 16 cnt(int) + pad + 80 float4 partials + pad
    const size_t diagF  = 8 * N_ROWS;
    auto slabB = [](int ns) { return (size_t)ns * 2 * 10 * 16384 * sizeof(u16); };

    int*    cnt      = (int*)wsf;
    float4* partials = (float4*)(wsf + 64);
    float*  diagPart = wsf + hdrF;

    // fp8 tier: [hdr | diagPart | Xq(4MB) | Yq(4MB) | slabs]
    const size_t coreB_fp8 = (hdrF + diagF) * sizeof(float) + 2 * trElems * sizeof(u8);
    int nsplit = 0;
    if      (ws_size >= coreB_fp8 + slabB(32)) nsplit = 32;
    else if (ws_size >= coreB_fp8 + slabB(16)) nsplit = 16;

    if (nsplit) {
        u8* Xq = (u8*)(diagPart + diagF);
        u8* Yq = Xq + trElems;
        u16* slabs = (u16*)(Yq + trElems);
        convert_fp8<<<1024, NT, 0, stream>>>(X, Y, Xq, Yq, diagPart, cnt);
        syrk_fp8<<<dim3(nsplit, 10, 2), NT, 0, stream>>>(Xq, Yq, slabs, N_ROWS / nsplit);
        pass2_packed<<<80, 256, 0, stream>>>(slabs, diagPart, partials, cnt, out, nsplit);
        return;
    }

    // bf16 atomic tier
    const size_t coreB_bf16 = (hdrF + diagF) * sizeof(float) + 2 * trElems * sizeof(u16);
    if (ws_size >= coreB_bf16 + 2 * (size_t)DIMS * DIMS * sizeof(float) + 80 * sizeof(float4)) {
        u16* Xh = (u16*)(diagPart + diagF);
        u16* Yh = Xh + trElems;
        float* Aslab = (float*)(Yh + trElems);
        float* Bslab = Aslab + DIMS * DIMS;
        float4* part2 = (float4*)(Bslab + DIMS * DIMS);
        hipMemsetAsync(Aslab, 0, 2 * (size_t)DIMS * DIMS * sizeof(float), stream);
        convert_diag<<<1024, NT, 0, stream>>>(X, Y, Xh, Yh, diagPart, cnt);
        syrk_bf16<<<dim3(32, 10, 2), NT, 0, stream>>>(Xh, Yh, Aslab, Bslab, N_ROWS / 32);
        pass2_sym<<<80, 256, 0, stream>>>(Aslab, Bslab, diagPart, part2);
        finalize_partials<<<1, 64, 0, stream>>>(part2, 80, out);
        return;
    }

    // fp32 vector fallback
    {
        const size_t slabElems = (size_t)DIMS * DIMS;
        const size_t hdr = 64;
        const bool slabs2 = ws_size >= (hdr + 16 * slabElems) * sizeof(float);
        const int  nslab = slabs2 ? KSPLIT : 1;
        float* Abase = wsf + hdr;
        float* Bbase = Abase + (size_t)nslab * slabElems;

        hipMemsetAsync(d_ws, 0, hdr * sizeof(float), stream);
        if (!slabs2) hipMemsetAsync(Abase, 0, 2 * slabElems * sizeof(float), stream);

        dim3 sg(64, KSPLIT);
        syrk_kernel<<<sg, NT, 0, stream>>>(X, Y, Abase, Bbase, slabs2 ? 1 : 0);
        diag_kernel<<<256, 256, 0, stream>>>(X, Y, wsf);
        pass2_kernel<<<256, 256, 0, stream>>>(Abase, Bbase, wsf, nslab);
        finalize_kernel<<<1, 64, 0, stream>>>(wsf, out);
    }
}

// Round 9
// 93.142 us; speedup vs baseline: 2.4662x; 1.0290x over previous
//
#include <hip/hip_runtime.h>
#include <cstdint>

#define N_ROWS 8192
#define DIMS   512
#define NT     256

typedef unsigned short u16;
typedef unsigned char  u8;
typedef __attribute__((ext_vector_type(8))) short s8v;            // 8 bf16 MFMA A/B frag
typedef __attribute__((ext_vector_type(4))) float f4v;            // MFMA C/D frag
typedef __attribute__((ext_vector_type(2))) float f2v;
typedef __attribute__((ext_vector_type(8))) unsigned short u16x8;

__device__ __forceinline__ u16 f2bf(float f) {
    unsigned u = __float_as_uint(f);
    unsigned r = (u + 0x7fff + ((u >> 16) & 1)) >> 16;
    return (u16)r;
}
__device__ __forceinline__ float bf2f(u16 h) { return __uint_as_float(((unsigned)h) << 16); }

__device__ __forceinline__ void gl16(const void* g, void* l) {
    auto gp = (const __attribute__((address_space(1))) unsigned int*)(uintptr_t)g;
    auto lp = (__attribute__((address_space(3))) unsigned int*)(uintptr_t)l;
    __builtin_amdgcn_global_load_lds(gp, lp, 16, 0, 0);
}

// pack 4 floats -> 4 fp8 e4m3 (OCP) via v_cvt_pk_fp8_f32 (RNE)
__device__ __forceinline__ unsigned pk4fp8(float a, float b, float c, float d) {
    int r = 0;
    r = __builtin_amdgcn_cvt_pk_fp8_f32(a, b, r, false);   // bytes 0-1
    r = __builtin_amdgcn_cvt_pk_fp8_f32(c, d, r, true);    // bytes 2-3
    return (unsigned)r;
}
// unpack 4 fp8 e4m3 -> 4 floats
__device__ __forceinline__ void up4fp8(unsigned v, float* o) {
    f2v lo = __builtin_amdgcn_cvt_pk_f32_fp8((int)v, false);
    f2v hi = __builtin_amdgcn_cvt_pk_f32_fp8((int)v, true);
    o[0] = lo[0]; o[1] = lo[1]; o[2] = hi[0]; o[3] = hi[1];
}

// ============ convert + transpose -> fp8 [512][8192] + diag partials + cnt zero ============
__global__ __launch_bounds__(NT) void convert_fp8(
    const float* __restrict__ X, const float* __restrict__ Y,
    u8* __restrict__ Xq, u8* __restrict__ Yq,
    float* __restrict__ diagPart, int* __restrict__ cnt)
{
    const int b  = blockIdx.x;
    const int nt = b & 127;
    const int dt = b >> 7;
    const int tid = threadIdx.x;

    if (b == 0 && tid < 16) cnt[tid] = 0;

    __shared__ float tx[64][65];
    __shared__ float ty[64][65];

    const int c4 = tid & 15, rr = tid >> 4;
#pragma unroll
    for (int rp = 0; rp < 4; ++rp) {
        const int row = rp * 16 + rr;
        const size_t gbase = (size_t)(nt * 64 + row) * DIMS + dt * 64 + c4 * 4;
        float4 vx = *(const float4*)&X[gbase];
        float4 vy = *(const float4*)&Y[gbase];
        tx[row][c4 * 4 + 0] = vx.x; tx[row][c4 * 4 + 1] = vx.y;
        tx[row][c4 * 4 + 2] = vx.z; tx[row][c4 * 4 + 3] = vx.w;
        ty[row][c4 * 4 + 0] = vy.x; ty[row][c4 * 4 + 1] = vy.y;
        ty[row][c4 * 4 + 2] = vy.z; ty[row][c4 * 4 + 3] = vy.w;
        float d = vx.x * vy.x + vx.y * vy.y + vx.z * vy.z + vx.w * vy.w;
        d += __shfl_xor(d, 1); d += __shfl_xor(d, 2);
        d += __shfl_xor(d, 4); d += __shfl_xor(d, 8);
        if (c4 == 0) diagPart[dt * N_ROWS + nt * 64 + row] = d;
    }
    __syncthreads();

    const int d = tid >> 2, ns = (tid & 3) * 16;
    const size_t ob = (size_t)(dt * 64 + d) * N_ROWS + nt * 64 + ns;
#pragma unroll
    for (int mat = 0; mat < 2; ++mat) {
        float (*tp)[65] = mat ? ty : tx;
        u8* Oq = mat ? Yq : Xq;
        float v[16];
#pragma unroll
        for (int i = 0; i < 16; ++i) v[i] = tp[ns + i][d];
        uint4 w;
        w.x = pk4fp8(v[0],  v[1],  v[2],  v[3]);
        w.y = pk4fp8(v[4],  v[5],  v[6],  v[7]);
        w.z = pk4fp8(v[8],  v[9],  v[10], v[11]);
        w.w = pk4fp8(v[12], v[13], v[14], v[15]);
        *(uint4*)&Oq[ob] = w;
    }
}

// ============ symmetric fp8 syrk, BK=64 double-buffer, fp8 slab epilogue ============
// grid (nsplit, 10, 2). 4 blocks/CU resident. Per wave 64x64 = 4x4 16x16x32
// fp8 tiles. Epilogue packs acc 4-rows-per-dword into fp8 slab (coalesced
// dword stores; layout is a private bijection shared with pass2).
__global__ __launch_bounds__(NT, 4) void syrk_fp8(
    const u8* __restrict__ Xq, const u8* __restrict__ Yq,
    unsigned* __restrict__ slabs32, int kchunk)
{
    __shared__ u8 smem[2 * 2 * 8192];   // [stage][stripe][128 rows * 64 B] = 32 KB

    const int tid = threadIdx.x;
    const int s = blockIdx.x, p = blockIdx.y, mat = blockIdx.z;
    const int ti_t[10] = {0,0,0,0,1,1,1,2,2,3};
    const int tj_t[10] = {0,1,2,3,1,2,3,2,3,3};
    const int m0 = ti_t[p] * 128, n0 = tj_t[p] * 128;
    const u8* Tq = mat ? Yq : Xq;

    const int w = tid >> 6, L = tid & 63;
    const int wm = (w >> 1) * 64, wn = (w & 1) * 64;
    const int lrow = L & 15, q = L >> 4;
    const int qh = q >> 1, ql = q & 1;

    f4v acc[4][4];
#pragma unroll
    for (int i = 0; i < 4; ++i)
#pragma unroll
        for (int j = 0; j < 4; ++j)
            acc[i][j] = (f4v){0.f, 0.f, 0.f, 0.f};

    const int kk0 = s * kchunk;
    const int nIter = kchunk / 64;

    auto loadStage = [&](int buf, int kb) {
        u8* dA = smem + buf * 16384;
        u8* dB = dA + 8192;
#pragma unroll
        for (int j = 0; j < 2; ++j) {
            const int slot = j * 256 + tid;
            const int row  = slot >> 2;
            const int c    = (slot & 3) ^ ((row >> 1) & 3);
            gl16(Tq + (size_t)(m0 + row) * N_ROWS + kb + c * 16, dA + slot * 16);
            gl16(Tq + (size_t)(n0 + row) * N_ROWS + kb + c * 16, dB + slot * 16);
        }
    };

    loadStage(0, kk0);

    for (int it = 0; it < nIter; ++it) {
        __syncthreads();                 // drains stage-it gl16s, syncs block
        if (it + 1 < nIter) loadStage((it + 1) & 1, kk0 + (it + 1) * 64);

        const u8* SA = smem + (it & 1) * 16384;
        const u8* SB = SA + 8192;
#pragma unroll
        for (int s2 = 0; s2 < 2; ++s2) {
            long a[4], b[4];
#pragma unroll
            for (int t = 0; t < 4; ++t) {
                const int rowA = wm + t * 16 + lrow;
                const int rowB = wn + t * 16 + lrow;
                const int cA = (s2 * 2 + qh) ^ ((rowA >> 1) & 3);
                const int cB = (s2 * 2 + qh) ^ ((rowB >> 1) & 3);
                a[t] = *(const long*)&SA[rowA * 64 + cA * 16 + ql * 8];
                b[t] = *(const long*)&SB[rowB * 64 + cB * 16 + ql * 8];
            }
#pragma unroll
            for (int ti2 = 0; ti2 < 4; ++ti2)
#pragma unroll
                for (int tj2 = 0; tj2 < 4; ++tj2)
                    acc[ti2][tj2] = __builtin_amdgcn_mfma_f32_16x16x32_fp8_fp8(
                        a[ti2], b[tj2], acc[ti2][tj2], 0, 0, 0);
        }
    }

    unsigned* dst = slabs32 + ((size_t)(s * 2 + mat) * 10 + p) * 4096;
#pragma unroll
    for (int ti2 = 0; ti2 < 4; ++ti2)
#pragma unroll
        for (int tj2 = 0; tj2 < 4; ++tj2) {
            const unsigned v = pk4fp8(acc[ti2][tj2][0], acc[ti2][tj2][1],
                                      acc[ti2][tj2][2], acc[ti2][tj2][3]);
            dst[(ti2 * 4 + tj2) * 256 + tid] = v;
        }
}

// ============ pass2 (fp8 slabs) + fused tiny finalize (last block of 80) ============
// 80 blocks x 256 = 20480 threads; each owns 2 dwords (8 elems) of one tile.
__global__ __launch_bounds__(256) void pass2_packed(
    const unsigned* __restrict__ slabs32, const float* __restrict__ diagPart,
    float4* __restrict__ partials, int* __restrict__ cnt, float* __restrict__ out,
    int nsplit)
{
    const int tid = threadIdx.x;
    const int g   = blockIdx.x * 256 + tid;        // 0..20479
    const int p   = g >> 11;                       // tile pair 0..9
    const int u2  = (g & 2047) * 2;                // dword index within tile
    const float wp = ((p == 0) | (p == 4) | (p == 7) | (p == 9)) ? 1.f : 2.f;

    float a[8] = {}, b[8] = {};
    for (int sb = 0; sb < nsplit; sb += 8) {
        uint2 va[8], vb[8];
#pragma unroll
        for (int i = 0; i < 8; ++i) {
            va[i] = *(const uint2*)&slabs32[((size_t)((sb + i) * 2 + 0) * 10 + p) * 4096 + u2];
            vb[i] = *(const uint2*)&slabs32[((size_t)((sb + i) * 2 + 1) * 10 + p) * 4096 + u2];
        }
#pragma unroll
        for (int i = 0; i < 8; ++i) {
            float ta[8], tb[8];
            up4fp8(va[i].x, ta); up4fp8(va[i].y, ta + 4);
            up4fp8(vb[i].x, tb); up4fp8(vb[i].y, tb + 4);
#pragma unroll
            for (int j = 0; j < 8; ++j) { a[j] += ta[j]; b[j] += tb[j]; }
        }
    }
    float sS = 0.f;
#pragma unroll
    for (int j = 0; j < 8; ++j) sS += a[j] * b[j];
    sS *= wp;

    float sD = 0.f, sD2 = 0.f;
    if (g < N_ROWS) {
        float d = 0.f;
#pragma unroll
        for (int dt = 0; dt < 8; ++dt) d += diagPart[dt * N_ROWS + g];
        sD = d; sD2 = d * d;
    }

    for (int off = 32; off; off >>= 1) {
        sS  += __shfl_xor(sS,  off);
        sD  += __shfl_xor(sD,  off);
        sD2 += __shfl_xor(sD2, off);
    }
    __shared__ float red[3][4];
    const int w = tid >> 6, L = tid & 63;
    if (L == 0) { red[0][w] = sS; red[1][w] = sD; red[2][w] = sD2; }
    __syncthreads();

    __shared__ int sflag;
    if (tid == 0) {
        partials[blockIdx.x] = make_float4(
            red[0][0] + red[0][1] + red[0][2] + red[0][3],
            red[1][0] + red[1][1] + red[1][2] + red[1][3],
            red[2][0] + red[2][1] + red[2][2] + red[2][3], 0.f);
        __threadfence();                       // release partials
        sflag = (atomicAdd(&cnt[0], 1) == 79);
    }
    __syncthreads();
    if (!sflag) return;
    __threadfence();                           // acquire

    float fS = 0.f, fD = 0.f, fD2 = 0.f;
    if (tid < 80) {
        float4 v = partials[tid];
        fS = v.x; fD = v.y; fD2 = v.z;
    }
    for (int off = 32; off; off >>= 1) {
        fS  += __shfl_xor(fS,  off);
        fD  += __shfl_xor(fD,  off);
        fD2 += __shfl_xor(fD2, off);
    }
    if (L == 0) { red[0][w] = fS; red[1][w] = fD; red[2][w] = fD2; }
    __syncthreads();
    if (tid == 0) {
        const double S   = (double)(red[0][0] + red[0][1] + red[0][2] + red[0][3]);
        const double ds  = (double)(red[1][0] + red[1][1] + red[1][2] + red[1][3]);
        const double dsq = (double)(red[2][0] + red[2][1] + red[2][2] + red[2][3]);
        const double loss =
            (S - dsq) / ((double)N_ROWS * (double)(N_ROWS - 1)) - 2.0 * ds / (double)N_ROWS;
        out[0] = (float)loss;
    }
}

// ====================== fallback tiers (proven, unchanged) ======================

__global__ __launch_bounds__(NT) void convert_diag(
    const float* __restrict__ X, const float* __restrict__ Y,
    u16* __restrict__ Xh, u16* __restrict__ Yh,
    float* __restrict__ diagPart, int* __restrict__ cnt)
{
    const int b  = blockIdx.x;
    const int nt = b & 127;
    const int dt = b >> 7;
    const int tid = threadIdx.x;

    if (b == 0 && tid < 16) cnt[tid] = 0;

    __shared__ float tx[64][65];
    __shared__ float ty[64][65];

    const int c4 = tid & 15, rr = tid >> 4;
#pragma unroll
    for (int rp = 0; rp < 4; ++rp) {
        const int row = rp * 16 + rr;
        const size_t gbase = (size_t)(nt * 64 + row) * DIMS + dt * 64 + c4 * 4;
        float4 vx = *(const float4*)&X[gbase];
        float4 vy = *(const float4*)&Y[gbase];
        tx[row][c4 * 4 + 0] = vx.x; tx[row][c4 * 4 + 1] = vx.y;
        tx[row][c4 * 4 + 2] = vx.z; tx[row][c4 * 4 + 3] = vx.w;
        ty[row][c4 * 4 + 0] = vy.x; ty[row][c4 * 4 + 1] = vy.y;
        ty[row][c4 * 4 + 2] = vy.z; ty[row][c4 * 4 + 3] = vy.w;
        float d = vx.x * vy.x + vx.y * vy.y + vx.z * vy.z + vx.w * vy.w;
        d += __shfl_xor(d, 1); d += __shfl_xor(d, 2);
        d += __shfl_xor(d, 4); d += __shfl_xor(d, 8);
        if (c4 == 0) diagPart[dt * N_ROWS + nt * 64 + row] = d;
    }
    __syncthreads();

    const int d = tid >> 2, ns = (tid & 3) * 16;
    const size_t ob = (size_t)(dt * 64 + d) * N_ROWS + nt * 64 + ns;
#pragma unroll
    for (int mat = 0; mat < 2; ++mat) {
        float (*tp)[65] = mat ? ty : tx;
        u16* Oh = mat ? Yh : Xh;
        u16x8 h0, h1;
#pragma unroll
        for (int i = 0; i < 8; ++i) {
            h0[i] = f2bf(tp[ns + i][d]);
            h1[i] = f2bf(tp[ns + 8 + i][d]);
        }
        *(u16x8*)&Oh[ob]     = h0;
        *(u16x8*)&Oh[ob + 8] = h1;
    }
}

__global__ __launch_bounds__(NT, 4) void syrk_bf16(
    const u16* __restrict__ Xh, const u16* __restrict__ Yh,
    float* __restrict__ Aslab, float* __restrict__ Bslab, int kchunk)
{
    __shared__ u16 smem[2 * 2 * 4096];   // 32 KB

    const int tid = threadIdx.x;
    const int s = blockIdx.x, p = blockIdx.y, mat = blockIdx.z;
    const int ti_t[10] = {0,0,0,0,1,1,1,2,2,3};
    const int tj_t[10] = {0,1,2,3,1,2,3,2,3,3};
    const int m0 = ti_t[p] * 128, n0 = tj_t[p] * 128;
    const u16* Th = mat ? Yh : Xh;

    const int w = tid >> 6, L = tid & 63;
    const int wm = (w >> 1) * 64, wn = (w & 1) * 64;
    const int lrow = L & 15, q = L >> 4;

    f4v acc[4][4];
#pragma unroll
    for (int i = 0; i < 4; ++i)
#pragma unroll
        for (int j = 0; j < 4; ++j)
            acc[i][j] = (f4v){0.f, 0.f, 0.f, 0.f};

    const int kk0 = s * kchunk;
    const int nIter = kchunk / 32;

    auto loadStage = [&](int buf, int kb) {
        u16* dA = smem + buf * 8192;
        u16* dB = dA + 4096;
#pragma unroll
        for (int j = 0; j < 2; ++j) {
            const int slot = j * 256 + tid;
            const int row  = slot >> 2;
            const int c    = (slot & 3) ^ ((row >> 1) & 3);
            gl16(Th + (size_t)(m0 + row) * N_ROWS + kb + c * 8, dA + slot * 8);
            gl16(Th + (size_t)(n0 + row) * N_ROWS + kb + c * 8, dB + slot * 8);
        }
    };

    loadStage(0, kk0);

    for (int it = 0; it < nIter; ++it) {
        __syncthreads();
        if (it + 1 < nIter) loadStage((it + 1) & 1, kk0 + (it + 1) * 32);

        const u16* SA = smem + (it & 1) * 8192;
        const u16* SB = SA + 4096;
        s8v a[4], b[4];
#pragma unroll
        for (int t = 0; t < 4; ++t) {
            const int rowA = wm + t * 16 + lrow;
            const int rowB = wn + t * 16 + lrow;
            const int pA = q ^ ((rowA >> 1) & 3);
            const int pB = q ^ ((rowB >> 1) & 3);
            a[t] = *(const s8v*)&SA[rowA * 32 + pA * 8];
            b[t] = *(const s8v*)&SB[rowB * 32 + pB * 8];
        }
#pragma unroll
        for (int ti2 = 0; ti2 < 4; ++ti2)
#pragma unroll
            for (int tj2 = 0; tj2 < 4; ++tj2)
                acc[ti2][tj2] = __builtin_amdgcn_mfma_f32_16x16x32_bf16(
                    a[ti2], b[tj2], acc[ti2][tj2], 0, 0, 0);
    }

    float* G = mat ? Bslab : Aslab;
#pragma unroll
    for (int ti2 = 0; ti2 < 4; ++ti2)
#pragma unroll
        for (int tj2 = 0; tj2 < 4; ++tj2)
#pragma unroll
            for (int r = 0; r < 4; ++r) {
                const int row = m0 + wm + ti2 * 16 + q * 4 + r;
                const int col = n0 + wn + tj2 * 16 + lrow;
                atomicAdd(&G[row * DIMS + col], acc[ti2][tj2][r]);
            }
}

__global__ __launch_bounds__(256) void pass2_sym(
    const float* __restrict__ Aslab, const float* __restrict__ Bslab,
    const float* __restrict__ diagPart, float4* __restrict__ partials)
{
    const int tid = threadIdx.x;
    const int g   = blockIdx.x * 256 + tid;
    float sS = 0.f, sD = 0.f, sD2 = 0.f;
    for (int e = g; e < DIMS * DIMS; e += 20480) {
        const int r = e >> 9, c = e & 511;
        const float w = ((r >> 7) == (c >> 7)) ? 1.f : 2.f;
        sS += w * Aslab[e] * Bslab[e];
    }
    if (g < N_ROWS) {
        float d = 0.f;
#pragma unroll
        for (int dt = 0; dt < 8; ++dt) d += diagPart[dt * N_ROWS + g];
        sD = d; sD2 = d * d;
    }
    for (int off = 32; off; off >>= 1) {
        sS  += __shfl_xor(sS,  off);
        sD  += __shfl_xor(sD,  off);
        sD2 += __shfl_xor(sD2, off);
    }
    __shared__ float red[3][4];
    if ((tid & 63) == 0) {
        red[0][tid >> 6] = sS; red[1][tid >> 6] = sD; red[2][tid >> 6] = sD2;
    }
    __syncthreads();
    if (tid == 0)
        partials[blockIdx.x] = make_float4(
            red[0][0] + red[0][1] + red[0][2] + red[0][3],
            red[1][0] + red[1][1] + red[1][2] + red[1][3],
            red[2][0] + red[2][1] + red[2][2] + red[2][3], 0.f);
}

__global__ void finalize_partials(const float4* __restrict__ partials, int nb,
                                  float* __restrict__ out)
{
    const int tid = threadIdx.x;
    float sS = 0.f, sD = 0.f, sD2 = 0.f;
    for (int i = tid; i < nb; i += 64) {
        float4 v = partials[i];
        sS += v.x; sD += v.y; sD2 += v.z;
    }
    for (int off = 32; off; off >>= 1) {
        sS  += __shfl_xor(sS,  off);
        sD  += __shfl_xor(sD,  off);
        sD2 += __shfl_xor(sD2, off);
    }
    if (tid == 0) {
        const double offd = (double)sS - (double)sD2;
        const double loss =
            offd / ((double)N_ROWS * (double)(N_ROWS - 1)) - 2.0 * (double)sD / (double)N_ROWS;
        out[0] = (float)loss;
    }
}

#define TILE   64
#define KSPLIT 8
#define KCHUNK (N_ROWS / KSPLIT)
#define KB     16
__global__ __launch_bounds__(NT) void syrk_kernel(
    const float* __restrict__ X, const float* __restrict__ Y,
    float* __restrict__ Abase, float* __restrict__ Bbase, int useSlabs)
{
    const int tid = threadIdx.x;
    const int ta  = blockIdx.x >> 3;
    const int tb  = blockIdx.x & 7;
    const int s   = blockIdx.y;
    const int ca  = tid & 15;
    const int cb  = tid >> 4;

    __shared__ float4 sXA[KB * 16];
    __shared__ float4 sXB[KB * 16];
    __shared__ float4 sYA[KB * 16];
    __shared__ float4 sYB[KB * 16];

    const float4* Xv = (const float4*)X;
    const float4* Yv = (const float4*)Y;

    float aA[4][4] = {};
    float aB[4][4] = {};

    const int r0     = s * KCHUNK;
    const int rowOfT = tid >> 4;
    const int colOfT = tid & 15;

    for (int it = 0; it < KCHUNK / KB; ++it) {
        const int row  = r0 + it * KB + rowOfT;
        const int base = row * (DIMS / 4);
        __syncthreads();
        sXA[tid] = Xv[base + ta * 16 + colOfT];
        sXB[tid] = Xv[base + tb * 16 + colOfT];
        sYA[tid] = Yv[base + ta * 16 + colOfT];
        sYB[tid] = Yv[base + tb * 16 + colOfT];
        __syncthreads();
#pragma unroll
        for (int k = 0; k < KB; ++k) {
            float4 xa4 = sXA[k * 16 + ca];
            float4 xb4 = sXB[k * 16 + cb];
            float4 ya4 = sYA[k * 16 + ca];
            float4 yb4 = sYB[k * 16 + cb];
            float xa[4] = {xa4.x, xa4.y, xa4.z, xa4.w};
            float xb[4] = {xb4.x, xb4.y, xb4.z, xb4.w};
            float ya[4] = {ya4.x, ya4.y, ya4.z, ya4.w};
            float yb[4] = {yb4.x, yb4.y, yb4.z, yb4.w};
#pragma unroll
            for (int i = 0; i < 4; ++i)
#pragma unroll
                for (int j = 0; j < 4; ++j) {
                    aA[i][j] = fmaf(xa[i], xb[j], aA[i][j]);
                    aB[i][j] = fmaf(ya[i], yb[j], aB[i][j]);
                }
        }
    }

    const size_t slabElems = (size_t)DIMS * DIMS;
    float* Adst = Abase + (useSlabs ? (size_t)s * slabElems : 0);
    float* Bdst = Bbase + (useSlabs ? (size_t)s * slabElems : 0);

#pragma unroll
    for (int i = 0; i < 4; ++i) {
        const int    ag    = ta * TILE + ca * 4 + i;
        const int    cbase = tb * TILE + cb * 4;
        const size_t idx   = (size_t)ag * DIMS + cbase;
        if (useSlabs) {
            *(float4*)(Adst + idx) = make_float4(aA[i][0], aA[i][1], aA[i][2], aA[i][3]);
            *(float4*)(Bdst + idx) = make_float4(aB[i][0], aB[i][1], aB[i][2], aB[i][3]);
        } else {
#pragma unroll
            for (int j = 0; j < 4; ++j) {
                atomicAdd(Adst + idx + j, aA[i][j]);
                atomicAdd(Bdst + idx + j, aB[i][j]);
            }
        }
    }
}

__global__ __launch_bounds__(256) void diag_kernel(
    const float* __restrict__ X, const float* __restrict__ Y,
    float* __restrict__ scal)
{
    const int tid  = threadIdx.x;
    const int lane = tid & 63;
    const int wave = blockIdx.x * 4 + (tid >> 6);
    const float4* Xv = (const float4*)X;
    const float4* Yv = (const float4*)Y;

    float dsum = 0.f, dsq = 0.f;
    for (int r = 0; r < 8; ++r) {
        const int row  = wave * 8 + r;
        const int base = row * (DIMS / 4) + lane * 2;
        float4 x0 = Xv[base], x1 = Xv[base + 1];
        float4 y0 = Yv[base], y1 = Yv[base + 1];
        float v = x0.x * y0.x + x0.y * y0.y + x0.z * y0.z + x0.w * y0.w
                + x1.x * y1.x + x1.y * y1.y + x1.z * y1.z + x1.w * y1.w;
        for (int off = 32; off; off >>= 1) v += __shfl_xor(v, off);
        if (lane == 0) { dsum += v; dsq += v * v; }
    }
    if (lane == 0) {
        atomicAdd(scal + 0, dsum);
        atomicAdd(scal + 1, dsq);
    }
}

__global__ __launch_bounds__(256) void pass2_kernel(
    const float* __restrict__ Abase, const float* __restrict__ Bbase,
    float* __restrict__ scal, int nslab)
{
    const int tid = threadIdx.x;
    const int g   = blockIdx.x * 256 + tid;
    const size_t slabElems = (size_t)DIMS * DIMS;
    float local = 0.f;
    for (int e = g; e < (int)slabElems; e += 65536) {
        float a = 0.f, b = 0.f;
        for (int s2 = 0; s2 < nslab; ++s2) {
            a += Abase[(size_t)s2 * slabElems + e];
            b += Bbase[(size_t)s2 * slabElems + e];
        }
        local += a * b;
    }
    for (int off = 32; off; off >>= 1) local += __shfl_xor(local, off);
    __shared__ float red[4];
    if ((tid & 63) == 0) red[tid >> 6] = local;
    __syncthreads();
    if (tid == 0) atomicAdd(scal + 2, red[0] + red[1] + red[2] + red[3]);
}

__global__ void finalize_kernel(const float* __restrict__ scal,
                                float* __restrict__ out)
{
    if (threadIdx.x == 0 && blockIdx.x == 0) {
        const double S   = (double)scal[2];
        const double dsq = (double)scal[1];
        const double ds  = (double)scal[0];
        const double off = S - dsq;
        const double loss =
            off / ((double)N_ROWS * (double)(N_ROWS - 1)) - 2.0 * ds / (double)N_ROWS;
        out[0] = (float)loss;
    }
}

extern "C" void kernel_launch(void* const* d_in, const int* in_sizes, int n_in,
                              void* d_out, int out_size, void* d_ws, size_t ws_size,
                              hipStream_t stream)
{
    const float* X = (const float*)d_in[0];
    const float* Y = (const float*)d_in[1];
    float* out = (float*)d_out;
    float* wsf = (float*)d_ws;

    const size_t trElems = (size_t)DIMS * N_ROWS;             // 4,194,304 elems/matrix
    const size_t hdrF   = 448;           // 16 cnt(int) + pad + 80 float4 partials + pad
    const size_t diagF  = 8 * N_ROWS;
    // fp8 slabs: ns*2*10 tiles x 4096 dwords
    auto slabB = [](int ns) { return (size_t)ns * 2 * 10 * 4096 * sizeof(unsigned); };

    int*    cnt      = (int*)wsf;
    float4* partials = (float4*)(wsf + 64);
    float*  diagPart = wsf + hdrF;

    // fp8 tier: [hdr | diagPart | Xq(4MB) | Yq(4MB) | slabs]
    const size_t coreB_fp8 = (hdrF + diagF) * sizeof(float) + 2 * trElems * sizeof(u8);
    int nsplit = 0;
    if      (ws_size >= coreB_fp8 + slabB(32)) nsplit = 32;
    else if (ws_size >= coreB_fp8 + slabB(16)) nsplit = 16;

    if (nsplit) {
        u8* Xq = (u8*)(diagPart + diagF);
        u8* Yq = Xq + trElems;
        unsigned* slabs32 = (unsigned*)(Yq + trElems);
        convert_fp8<<<1024, NT, 0, stream>>>(X, Y, Xq, Yq, diagPart, cnt);
        syrk_fp8<<<dim3(nsplit, 10, 2), NT, 0, stream>>>(Xq, Yq, slabs32, N_ROWS / nsplit);
        pass2_packed<<<80, 256, 0, stream>>>(slabs32, diagPart, partials, cnt, out, nsplit);
        return;
    }

    // bf16 atomic tier
    const size_t coreB_bf16 = (hdrF + diagF) * sizeof(float) + 2 * trElems * sizeof(u16);
    if (ws_size >= coreB_bf16 + 2 * (size_t)DIMS * DIMS * sizeof(float) + 80 * sizeof(float4)) {
        u16* Xh = (u16*)(diagPart + diagF);
        u16* Yh = Xh + trElems;
        float* Aslab = (float*)(Yh + trElems);
        float* Bslab = Aslab + DIMS * DIMS;
        float4* part2 = (float4*)(Bslab + DIMS * DIMS);
        hipMemsetAsync(Aslab, 0, 2 * (size_t)DIMS * DIMS * sizeof(float), stream);
        convert_diag<<<1024, NT, 0, stream>>>(X, Y, Xh, Yh, diagPart, cnt);
        syrk_bf16<<<dim3(32, 10, 2), NT, 0, stream>>>(Xh, Yh, Aslab, Bslab, N_ROWS / 32);
        pass2_sym<<<80, 256, 0, stream>>>(Aslab, Bslab, diagPart, part2);
        finalize_partials<<<1, 64, 0, stream>>>(part2, 80, out);
        return;
    }

    // fp32 vector fallback
    {
        const size_t slabElems = (size_t)DIMS * DIMS;
        const size_t hdr = 64;
        const bool slabs2 = ws_size >= (hdr + 16 * slabElems) * sizeof(float);
        const int  nslab = slabs2 ? KSPLIT : 1;
        float* Abase = wsf + hdr;
        float* Bbase = Abase + (size_t)nslab * slabElems;

        hipMemsetAsync(d_ws, 0, hdr * sizeof(float), stream);
        if (!slabs2) hipMemsetAsync(Abase, 0, 2 * slabElems * sizeof(float), stream);

        dim3 sg(64, KSPLIT);
        syrk_kernel<<<sg, NT, 0, stream>>>(X, Y, Abase, Bbase, slabs2 ? 1 : 0);
        diag_kernel<<<256, 256, 0, stream>>>(X, Y, wsf);
        pass2_kernel<<<256, 256, 0, stream>>>(Abase, Bbase, wsf, nslab);
        finalize_kernel<<<1, 64, 0, stream>>>(wsf, out);
    }
}